// Round 2
// baseline (49619.153 us; speedup 1.0000x reference)
//
#include <hip/hip_runtime.h>
#include <hip/hip_bf16.h>
#include <math.h>

typedef __hip_bfloat16 bf16;

__device__ __forceinline__ float ldf(const float* p) { return *p; }
__device__ __forceinline__ float ldf(const bf16* p) { return __bfloat162float(*p); }
__device__ __forceinline__ void stf(float* p, float v) { *p = v; }
__device__ __forceinline__ void stf(bf16* p, float v) { *p = __float2bfloat16(v); }

__device__ __forceinline__ float gelu_tanh(float x) {
    float x3 = x * x * x;
    return 0.5f * x * (1.f + tanhf(0.7978845608028654f * (x + 0.044715f * x3)));
}

// ---------------- conv2d stride-2 pad-1 3x3 + bias + GELU ----------------
// grid: (OW/64, OH/4, OC), block 256. Weights for one oc staged in LDS.
template <typename TIn, typename TOut>
__global__ __launch_bounds__(256) void conv2d_k(
    const TIn* __restrict__ in, const float* __restrict__ w, const float* __restrict__ bias,
    TOut* __restrict__ out, int IC, int IH, int IW, int OH, int OW)
{
    __shared__ float ws[2304];  // up to IC=256 * 9
    int oc = blockIdx.z;
    int nt = IC * 9;
    for (int i = threadIdx.x; i < nt; i += 256) ws[i] = w[(size_t)oc * nt + i];
    __syncthreads();
    int ow = blockIdx.x * 64 + (threadIdx.x & 63);
    int oh = blockIdx.y * 4 + (threadIdx.x >> 6);
    float acc = bias[oc];
    int iy0 = oh * 2 - 1, ix0 = ow * 2 - 1;
    for (int ic = 0; ic < IC; ic++) {
        const TIn* ip = in + (size_t)ic * IH * IW;
        const float* wp = ws + ic * 9;
#pragma unroll
        for (int ky = 0; ky < 3; ky++) {
            int iy = iy0 + ky;
            if ((unsigned)iy >= (unsigned)IH) continue;
            const TIn* rp = ip + (size_t)iy * IW;
#pragma unroll
            for (int kx = 0; kx < 3; kx++) {
                int ix = ix0 + kx;
                if ((unsigned)ix < (unsigned)IW)
                    acc = fmaf(ldf(&rp[ix]), wp[ky * 3 + kx], acc);
            }
        }
    }
    stf(&out[((size_t)oc * OH + oh) * OW + ow], gelu_tanh(acc));
}

// ---------------- conv3d stride-2 pad-1 3x3x3 + bias + GELU ----------------
// grid: (OW/64, (OH/4)*OD, OC), block 256.
template <typename TIn, typename TOut>
__global__ __launch_bounds__(256) void conv3d_k(
    const TIn* __restrict__ in, const float* __restrict__ w, const float* __restrict__ bias,
    TOut* __restrict__ out, int IC, int ID, int IH, int IW,
    int OD, int OH, int OW, int OH4)
{
    __shared__ float ws[6912];  // up to IC=256 * 27
    int oc = blockIdx.z;
    int nt = IC * 27;
    for (int i = threadIdx.x; i < nt; i += 256) ws[i] = w[(size_t)oc * nt + i];
    __syncthreads();
    int od = blockIdx.y / OH4;
    int ohb = blockIdx.y - od * OH4;
    int ow = blockIdx.x * 64 + (threadIdx.x & 63);
    int oh = ohb * 4 + (threadIdx.x >> 6);
    float acc = bias[oc];
    int iz0 = od * 2 - 1, iy0 = oh * 2 - 1, ix0 = ow * 2 - 1;
    size_t plane = (size_t)IH * IW;
    for (int ic = 0; ic < IC; ic++) {
        const TIn* ip = in + (size_t)ic * ID * plane;
        const float* wp = ws + ic * 27;
#pragma unroll
        for (int kz = 0; kz < 3; kz++) {
            int iz = iz0 + kz;
            if ((unsigned)iz >= (unsigned)ID) continue;
            const TIn* zp = ip + (size_t)iz * plane;
#pragma unroll
            for (int ky = 0; ky < 3; ky++) {
                int iy = iy0 + ky;
                if ((unsigned)iy >= (unsigned)IH) continue;
                const TIn* rp = zp + (size_t)iy * IW;
                const float* wr = wp + kz * 9 + ky * 3;
#pragma unroll
                for (int kx = 0; kx < 3; kx++) {
                    int ix = ix0 + kx;
                    if ((unsigned)ix < (unsigned)IW)
                        acc = fmaf(ldf(&rp[ix]), wr[kx], acc);
                }
            }
        }
    }
    stf(&out[(((size_t)oc * OD + od) * OH + oh) * OW + ow], gelu_tanh(acc));
}

// ---------------- fp32 tiled GEMM: C[M,N] = A[M,K] * B[K,N] (+bias) ----------------
// grid (N/64, M/64), block 256 (16x16 threads, 4x4 per thread), BK=16.
// biasMode: 0 none, 1 per-col, 2 per-row
__global__ __launch_bounds__(256) void gemm_k(
    const float* __restrict__ A, const float* __restrict__ B, const float* __restrict__ bias,
    float* __restrict__ C, int M, int N, int K, int biasMode)
{
    __shared__ float As[16][68];
    __shared__ float Bs[16][68];
    int tid = threadIdx.x;
    int n0 = blockIdx.x * 64, m0 = blockIdx.y * 64;
    int tx = tid & 15, ty = tid >> 4;
    float acc[4][4] = {};
    for (int k0 = 0; k0 < K; k0 += 16) {
#pragma unroll
        for (int i = 0; i < 4; i++) {
            int idx = tid + i * 256;
            int kk = idx & 15, row = idx >> 4;
            As[kk][row] = A[(size_t)(m0 + row) * K + (k0 + kk)];
        }
#pragma unroll
        for (int i = 0; i < 4; i++) {
            int idx = tid + i * 256;
            int col = idx & 63, kk = idx >> 6;
            Bs[kk][col] = B[(size_t)(k0 + kk) * N + (n0 + col)];
        }
        __syncthreads();
#pragma unroll
        for (int kk = 0; kk < 16; kk++) {
            float a[4], b[4];
#pragma unroll
            for (int i = 0; i < 4; i++) a[i] = As[kk][ty * 4 + i];
#pragma unroll
            for (int j = 0; j < 4; j++) b[j] = Bs[kk][tx * 4 + j];
#pragma unroll
            for (int i = 0; i < 4; i++)
#pragma unroll
                for (int j = 0; j < 4; j++)
                    acc[i][j] = fmaf(a[i], b[j], acc[i][j]);
        }
        __syncthreads();
    }
#pragma unroll
    for (int i = 0; i < 4; i++) {
        int row = m0 + ty * 4 + i;
#pragma unroll
        for (int j = 0; j < 4; j++) {
            int col = n0 + tx * 4 + j;
            float v = acc[i][j];
            if (biasMode == 1) v += bias[col];
            else if (biasMode == 2) v += bias[row];
            C[(size_t)row * N + col] = v;
        }
    }
}

// ---------------- concat p (d=0..2) and s (d=3) into feats [512,4,32,64] ----------------
__global__ __launch_bounds__(256) void concat_k(
    const float* __restrict__ p2, const float* __restrict__ s2, float* __restrict__ feats)
{
    int idx = blockIdx.x * 256 + threadIdx.x;  // 512*8192 = 4194304
    int c = idx >> 13;
    int rem = idx & 8191;
    int d = rem >> 11;
    int sp = rem & 2047;
    float v = (d < 3) ? p2[((size_t)c * 3 + d) * 2048 + sp] : s2[(size_t)c * 2048 + sp];
    feats[idx] = v;
}

// ---------------- LayerNorm over C=512; x planar [C,P], y token-major [P,C] ----------------
__global__ __launch_bounds__(256) void ln_k(
    const float* __restrict__ x, const float* __restrict__ g, const float* __restrict__ b,
    float* __restrict__ y, int P)
{
    int pos = blockIdx.x, t = threadIdx.x;
    float v0 = x[(size_t)t * P + pos];
    float v1 = x[(size_t)(t + 256) * P + pos];
    float s = v0 + v1, ss = v0 * v0 + v1 * v1;
#pragma unroll
    for (int off = 32; off; off >>= 1) {
        s += __shfl_xor(s, off);
        ss += __shfl_xor(ss, off);
    }
    __shared__ float rs[4], rss[4];
    int wid = t >> 6;
    if ((t & 63) == 0) { rs[wid] = s; rss[wid] = ss; }
    __syncthreads();
    float S = rs[0] + rs[1] + rs[2] + rs[3];
    float SS = rss[0] + rss[1] + rss[2] + rss[3];
    float mu = S * (1.f / 512.f);
    float var = SS * (1.f / 512.f) - mu * mu;
    float rstd = rsqrtf(var + 1e-5f);
    y[(size_t)pos * 512 + t] = (v0 - mu) * rstd * g[t] + b[t];
    y[(size_t)pos * 512 + t + 256] = (v1 - mu) * rstd * g[t + 256] + b[t + 256];
}

// ---------------- neighborhood attention: one wave per (pos, head) ----------------
// qkv token-major [P,1536] = [q(8h x 64) | k | v]. D=4,H=32,W=64, window 5x7x7, scale=1/8.
__global__ __launch_bounds__(256) void natt_k(
    const float* __restrict__ qkv, float* __restrict__ o)
{
    int unit = blockIdx.x * 4 + (threadIdx.x >> 6);
    int lane = threadIdx.x & 63;
    int head = unit & 7;
    int pos = unit >> 3;
    int w = pos & 63, h = (pos >> 6) & 31, d = pos >> 11;
    float q = qkv[(size_t)pos * 1536 + head * 64 + lane] * 0.125f;
    float m = -1e30f, l = 0.f, oa = 0.f;
    for (int dz = -2; dz <= 2; dz++) {
        int zz = d + dz;
        if ((unsigned)zz >= 4u) continue;
        for (int dy = -3; dy <= 3; dy++) {
            int yy = h + dy;
            if ((unsigned)yy >= 32u) continue;
            int rb = (zz * 32 + yy) * 64;
            for (int dx = -3; dx <= 3; dx++) {
                int xx = w + dx;
                if ((unsigned)xx >= 64u) continue;
                size_t nb = (size_t)(rb + xx) * 1536 + 512 + head * 64 + lane;
                float t = q * qkv[nb];
#pragma unroll
                for (int off = 32; off; off >>= 1) t += __shfl_xor(t, off);
                float mn = fmaxf(m, t);
                float al = __expf(m - mn);
                float p = __expf(t - mn);
                l = l * al + p;
                oa = fmaf(p, qkv[nb + 512], oa * al);
                m = mn;
            }
        }
    }
    o[(size_t)pos * 512 + head * 64 + lane] = oa / l;
}

// ---------------- residual: lat[c,pos] += ptmp[pos,c] ----------------
__global__ __launch_bounds__(256) void resid_k(float* __restrict__ lat, const float* __restrict__ ptmp)
{
    int idx = blockIdx.x * 256 + threadIdx.x;  // c*8192 + pos
    int c = idx >> 13;
    int pos = idx & 8191;
    lat[idx] += ptmp[(size_t)pos * 512 + c];
}

// ---------------- final copy fp32 -> fp32 out ----------------
__global__ __launch_bounds__(256) void copy_k(const float* __restrict__ lat, float* __restrict__ out)
{
    int idx = blockIdx.x * 256 + threadIdx.x;
    out[idx] = lat[idx];
}

extern "C" void kernel_launch(void* const* d_in, const int* in_sizes, int n_in,
                              void* d_out, int out_size, void* d_ws, size_t ws_size,
                              hipStream_t stream)
{
    const float* x2d = (const float*)d_in[0];
    const float* x3d = (const float*)d_in[1];
    const float* sw0 = (const float*)d_in[2];
    const float* sb0 = (const float*)d_in[3];
    const float* sw1 = (const float*)d_in[4];
    const float* sb1 = (const float*)d_in[5];
    const float* sw2 = (const float*)d_in[6];
    const float* sb2 = (const float*)d_in[7];
    const float* pw0 = (const float*)d_in[8];
    const float* pb0 = (const float*)d_in[9];
    const float* pw1 = (const float*)d_in[10];
    const float* pb1 = (const float*)d_in[11];
    const float* pw2 = (const float*)d_in[12];
    const float* pb2 = (const float*)d_in[13];
    const float* latw = (const float*)d_in[14];
    const float* latb = (const float*)d_in[15];
    const float* lng = (const float*)d_in[16];
    const float* lnb = (const float*)d_in[17];
    const float* qkvw = (const float*)d_in[18];
    const float* qkvb = (const float*)d_in[19];
    const float* projw = (const float*)d_in[20];
    const float* projb = (const float*)d_in[21];
    float* outp = (float*)d_out;

    char* ws = (char*)d_ws;
    // region layout (bytes):
    //   p0 region: 100,663,296 (p0 bf16) -> later qkv(50.3M f32)+y(16.8M)+attno(16.8M)+ptmp(16.8M)
    //   p1 region: 25,165,824 (p1 bf16); earlier hosts s0 bf16 (8.4M)
    //   p2 region: 12,582,912 (p2 f32); earlier hosts s1 bf16 (4.2M)
    //   s2: 4.2M f32, feats: 16.8M f32, lat: 16.8M f32   -> total 176,160,768 B
    size_t off_p0 = 0;
    size_t off_p1 = off_p0 + 100663296ull;
    size_t off_p2 = off_p1 + 25165824ull;
    size_t off_s2 = off_p2 + 12582912ull;
    size_t off_ft = off_s2 + 4194304ull;
    size_t off_lat = off_ft + 16777216ull;

    bf16* s0 = (bf16*)(ws + off_p1);
    bf16* s1 = (bf16*)(ws + off_p2);
    float* s2 = (float*)(ws + off_s2);
    bf16* p0 = (bf16*)(ws + off_p0);
    bf16* p1 = (bf16*)(ws + off_p1);
    float* p2 = (float*)(ws + off_p2);
    float* feats = (float*)(ws + off_ft);
    float* lat = (float*)(ws + off_lat);
    float* qkv = (float*)(ws + off_p0);
    float* y = (float*)(ws + off_p0 + 50331648ull);
    float* attno = (float*)(ws + off_p0 + 67108864ull);
    float* ptmp = (float*)(ws + off_p0 + 83886080ull);

    // surface path: [8,256,512] -> [128,128,256] -> [256,64,128] -> [512,32,64]
    conv2d_k<float, bf16><<<dim3(4, 32, 128), 256, 0, stream>>>(x2d, sw0, sb0, s0, 8, 256, 512, 128, 256);
    conv2d_k<bf16, bf16><<<dim3(2, 16, 256), 256, 0, stream>>>(s0, sw1, sb1, s1, 128, 128, 256, 64, 128);
    conv2d_k<bf16, float><<<dim3(1, 8, 512), 256, 0, stream>>>(s1, sw2, sb2, s2, 256, 64, 128, 32, 64);

    // pressure path: [5,24,256,512] -> [128,12,128,256] -> [256,6,64,128] -> [512,3,32,64]
    conv3d_k<float, bf16><<<dim3(4, 384, 128), 256, 0, stream>>>(x3d, pw0, pb0, p0, 5, 24, 256, 512, 12, 128, 256, 32);
    conv3d_k<bf16, bf16><<<dim3(2, 96, 256), 256, 0, stream>>>(p0, pw1, pb1, p1, 128, 12, 128, 256, 6, 64, 128, 16);
    conv3d_k<bf16, float><<<dim3(1, 24, 512), 256, 0, stream>>>(p1, pw2, pb2, p2, 256, 6, 64, 128, 3, 32, 64, 8);

    // concat + lateral 1x1x1 conv (as GEMM: [512 oc,512 ic] x [512 ic,8192 pos])
    concat_k<<<16384, 256, 0, stream>>>(p2, s2, feats);
    gemm_k<<<dim3(128, 8), 256, 0, stream>>>(latw, feats, latb, lat, 512, 8192, 512, 2);

    // 3 rounds of neighborhood attention
    for (int r = 0; r < 3; r++) {
        ln_k<<<8192, 256, 0, stream>>>(lat, lng + r * 512, lnb + r * 512, y, 8192);
        gemm_k<<<dim3(24, 128), 256, 0, stream>>>(
            y, qkvw + (size_t)r * 512 * 1536, qkvb + r * 1536, qkv, 8192, 1536, 512, 1);
        natt_k<<<16384, 256, 0, stream>>>(qkv, attno);
        gemm_k<<<dim3(8, 128), 256, 0, stream>>>(
            attno, projw + (size_t)r * 512 * 512, projb + r * 512, ptmp, 8192, 512, 512, 1);
        resid_k<<<16384, 256, 0, stream>>>(lat, ptmp);
    }

    copy_k<<<16384, 256, 0, stream>>>(lat, outp);
}

// Round 3
// 10328.164 us; speedup vs baseline: 4.8043x; 4.8043x over previous
//
#include <hip/hip_runtime.h>
#include <hip/hip_bf16.h>
#include <math.h>

typedef __hip_bfloat16 bf16;

__device__ __forceinline__ float ldf(const float* p) { return *p; }
__device__ __forceinline__ float ldf(const bf16* p) { return __bfloat162float(*p); }
__device__ __forceinline__ void stf(float* p, float v) { *p = v; }
__device__ __forceinline__ void stf(bf16* p, float v) { *p = __float2bfloat16(v); }

__device__ __forceinline__ float gelu_tanh(float x) {
    float x3 = x * x * x;
    return 0.5f * x * (1.f + tanhf(0.7978845608028654f * (x + 0.044715f * x3)));
}

// ================= tiled conv3d: stride-2 pad-1 3x3x3 + bias + GELU =================
// Block: 256 threads = 32(ow) x 4(oh) positions x 2 oc-halves; computes 64 ocs.
// Grid: (OW/32, OD*(OH/4), OC/64).  K-blocked over IC in chunks of ICB.
// LDS: xs[ICB][3][9][65] fp32 + wsh[ICB*27][68] fp32 (tap-major, oc contiguous).
template <typename TIn, typename TOut, int IC, int ICB>
__global__ __launch_bounds__(256) void conv3d_t(
    const TIn* __restrict__ in, const float* __restrict__ w, const float* __restrict__ bias,
    TOut* __restrict__ out, int ID, int IH, int IW, int OD, int OH, int OW, int OHB)
{
    constexpr int XT = 65, YT = 9, ZT = 3, WS = 68;
    constexpr int NX = ICB * ZT * YT * XT;
    constexpr int NTAP = ICB * 27;
    __shared__ float xs[NX];
    __shared__ float wsh[NTAP * WS];
    int tid = threadIdx.x;
    int bx = blockIdx.x, by = blockIdx.y;
    int oc0 = blockIdx.z * 64;
    int od = by / OHB, ohb = by - od * OHB;
    int oh0 = ohb * 4;
    int owl = tid & 31, ohl = (tid >> 5) & 3, half = tid >> 7;
    int ix0 = bx * 64 - 1, iy0 = oh0 * 2 - 1, iz0 = od * 2 - 1;
    float acc[32];
#pragma unroll
    for (int j = 0; j < 32; j++) acc[j] = bias[oc0 + half * 32 + j];

    for (int ic0 = 0; ic0 < IC; ic0 += ICB) {
        __syncthreads();
        for (int i = tid; i < NX; i += 256) {
            int icl = i / (ZT * YT * XT);
            int r = i - icl * (ZT * YT * XT);
            int zz = r / (YT * XT);
            int r2 = r - zz * (YT * XT);
            int yy = r2 / XT;
            int xx = r2 - yy * XT;
            int iz = iz0 + zz, iy = iy0 + yy, ix = ix0 + xx;
            float v = 0.f;
            if ((unsigned)iz < (unsigned)ID && (unsigned)iy < (unsigned)IH && (unsigned)ix < (unsigned)IW)
                v = ldf(&in[(((size_t)(ic0 + icl) * ID + iz) * IH + iy) * IW + ix]);
            xs[i] = v;
        }
        for (int i = tid; i < 64 * NTAP; i += 256) {
            int ocl = i / NTAP;
            int t = i - ocl * NTAP;
            wsh[t * WS + ocl] = w[((size_t)(oc0 + ocl) * IC + ic0) * 27 + t];
        }
        __syncthreads();
#pragma unroll 1
        for (int icl = 0; icl < ICB; icl++) {
#pragma unroll
            for (int kz = 0; kz < 3; kz++) {
#pragma unroll
                for (int ky = 0; ky < 3; ky++) {
                    int xb = ((icl * ZT + kz) * YT + (2 * ohl + ky)) * XT + 2 * owl;
#pragma unroll
                    for (int kx = 0; kx < 3; kx++) {
                        float xv = xs[xb + kx];
                        const float4* wr = (const float4*)&wsh[(icl * 27 + kz * 9 + ky * 3 + kx) * WS + half * 32];
#pragma unroll
                        for (int j4 = 0; j4 < 8; j4++) {
                            float4 wv = wr[j4];
                            acc[j4 * 4 + 0] = fmaf(xv, wv.x, acc[j4 * 4 + 0]);
                            acc[j4 * 4 + 1] = fmaf(xv, wv.y, acc[j4 * 4 + 1]);
                            acc[j4 * 4 + 2] = fmaf(xv, wv.z, acc[j4 * 4 + 2]);
                            acc[j4 * 4 + 3] = fmaf(xv, wv.w, acc[j4 * 4 + 3]);
                        }
                    }
                }
            }
        }
    }
    int ow = bx * 32 + owl, oh = oh0 + ohl;
#pragma unroll
    for (int j = 0; j < 32; j++) {
        int oc = oc0 + half * 32 + j;
        stf(&out[(((size_t)oc * OD + od) * OH + oh) * OW + ow], gelu_tanh(acc[j]));
    }
}

// ================= tiled conv2d: stride-2 pad-1 3x3 + bias + GELU =================
// Block: 256 threads = 32(ow) x 8(oh) positions; each thread computes 32 ocs.
// Grid: (OW/32, OH/8, OC/32).  LDS: xs[ICB][17][65] + wsh[ICB*9][36].
template <typename TIn, typename TOut, int IC, int ICB>
__global__ __launch_bounds__(256) void conv2d_t(
    const TIn* __restrict__ in, const float* __restrict__ w, const float* __restrict__ bias,
    TOut* __restrict__ out, int IH, int IW, int OH, int OW)
{
    constexpr int XT = 65, YT = 17, WS = 36;
    constexpr int NX = ICB * YT * XT;
    constexpr int NTAP = ICB * 9;
    __shared__ float xs[NX];
    __shared__ float wsh[NTAP * WS];
    int tid = threadIdx.x;
    int bx = blockIdx.x, by = blockIdx.y;
    int oc0 = blockIdx.z * 32;
    int oh0 = by * 8;
    int owl = tid & 31, ohl = tid >> 5;
    int ix0 = bx * 64 - 1, iy0 = oh0 * 2 - 1;
    float acc[32];
#pragma unroll
    for (int j = 0; j < 32; j++) acc[j] = bias[oc0 + j];

    for (int ic0 = 0; ic0 < IC; ic0 += ICB) {
        __syncthreads();
        for (int i = tid; i < NX; i += 256) {
            int icl = i / (YT * XT);
            int r = i - icl * (YT * XT);
            int yy = r / XT;
            int xx = r - yy * XT;
            int iy = iy0 + yy, ix = ix0 + xx;
            float v = 0.f;
            if ((unsigned)iy < (unsigned)IH && (unsigned)ix < (unsigned)IW)
                v = ldf(&in[((size_t)(ic0 + icl) * IH + iy) * IW + ix]);
            xs[i] = v;
        }
        for (int i = tid; i < 32 * NTAP; i += 256) {
            int ocl = i / NTAP;
            int t = i - ocl * NTAP;
            wsh[t * WS + ocl] = w[((size_t)(oc0 + ocl) * IC + ic0) * 9 + t];
        }
        __syncthreads();
#pragma unroll 1
        for (int icl = 0; icl < ICB; icl++) {
#pragma unroll
            for (int ky = 0; ky < 3; ky++) {
                int xb = (icl * YT + (2 * ohl + ky)) * XT + 2 * owl;
#pragma unroll
                for (int kx = 0; kx < 3; kx++) {
                    float xv = xs[xb + kx];
                    const float4* wr = (const float4*)&wsh[(icl * 9 + ky * 3 + kx) * WS];
#pragma unroll
                    for (int j4 = 0; j4 < 8; j4++) {
                        float4 wv = wr[j4];
                        acc[j4 * 4 + 0] = fmaf(xv, wv.x, acc[j4 * 4 + 0]);
                        acc[j4 * 4 + 1] = fmaf(xv, wv.y, acc[j4 * 4 + 1]);
                        acc[j4 * 4 + 2] = fmaf(xv, wv.z, acc[j4 * 4 + 2]);
                        acc[j4 * 4 + 3] = fmaf(xv, wv.w, acc[j4 * 4 + 3]);
                    }
                }
            }
        }
    }
    int ow = bx * 32 + owl, oh = oh0 + ohl;
#pragma unroll
    for (int j = 0; j < 32; j++) {
        int oc = oc0 + j;
        stf(&out[((size_t)oc * OH + oh) * OW + ow], gelu_tanh(acc[j]));
    }
}

// ---------------- fp32 tiled GEMM: C[M,N] = A[M,K] * B[K,N] (+bias) ----------------
__global__ __launch_bounds__(256) void gemm_k(
    const float* __restrict__ A, const float* __restrict__ B, const float* __restrict__ bias,
    float* __restrict__ C, int M, int N, int K, int biasMode)
{
    __shared__ float As[16][68];
    __shared__ float Bs[16][68];
    int tid = threadIdx.x;
    int n0 = blockIdx.x * 64, m0 = blockIdx.y * 64;
    int tx = tid & 15, ty = tid >> 4;
    float acc[4][4] = {};
    for (int k0 = 0; k0 < K; k0 += 16) {
#pragma unroll
        for (int i = 0; i < 4; i++) {
            int idx = tid + i * 256;
            int kk = idx & 15, row = idx >> 4;
            As[kk][row] = A[(size_t)(m0 + row) * K + (k0 + kk)];
        }
#pragma unroll
        for (int i = 0; i < 4; i++) {
            int idx = tid + i * 256;
            int col = idx & 63, kk = idx >> 6;
            Bs[kk][col] = B[(size_t)(k0 + kk) * N + (n0 + col)];
        }
        __syncthreads();
#pragma unroll
        for (int kk = 0; kk < 16; kk++) {
            float a[4], b[4];
#pragma unroll
            for (int i = 0; i < 4; i++) a[i] = As[kk][ty * 4 + i];
#pragma unroll
            for (int j = 0; j < 4; j++) b[j] = Bs[kk][tx * 4 + j];
#pragma unroll
            for (int i = 0; i < 4; i++)
#pragma unroll
                for (int j = 0; j < 4; j++)
                    acc[i][j] = fmaf(a[i], b[j], acc[i][j]);
        }
        __syncthreads();
    }
#pragma unroll
    for (int i = 0; i < 4; i++) {
        int row = m0 + ty * 4 + i;
#pragma unroll
        for (int j = 0; j < 4; j++) {
            int col = n0 + tx * 4 + j;
            float v = acc[i][j];
            if (biasMode == 1) v += bias[col];
            else if (biasMode == 2) v += bias[row];
            C[(size_t)row * N + col] = v;
        }
    }
}

// ---------------- concat p (d=0..2) and s (d=3) into feats [512,4,32,64] ----------------
__global__ __launch_bounds__(256) void concat_k(
    const float* __restrict__ p2, const float* __restrict__ s2, float* __restrict__ feats)
{
    int idx = blockIdx.x * 256 + threadIdx.x;  // 512*8192 = 4194304
    int c = idx >> 13;
    int rem = idx & 8191;
    int d = rem >> 11;
    int sp = rem & 2047;
    float v = (d < 3) ? p2[((size_t)c * 3 + d) * 2048 + sp] : s2[(size_t)c * 2048 + sp];
    feats[idx] = v;
}

// ---------------- LayerNorm over C=512; x planar [C,P], y token-major [P,C] ----------------
__global__ __launch_bounds__(256) void ln_k(
    const float* __restrict__ x, const float* __restrict__ g, const float* __restrict__ b,
    float* __restrict__ y, int P)
{
    int pos = blockIdx.x, t = threadIdx.x;
    float v0 = x[(size_t)t * P + pos];
    float v1 = x[(size_t)(t + 256) * P + pos];
    float s = v0 + v1, ss = v0 * v0 + v1 * v1;
#pragma unroll
    for (int off = 32; off; off >>= 1) {
        s += __shfl_xor(s, off);
        ss += __shfl_xor(ss, off);
    }
    __shared__ float rs[4], rss[4];
    int wid = t >> 6;
    if ((t & 63) == 0) { rs[wid] = s; rss[wid] = ss; }
    __syncthreads();
    float S = rs[0] + rs[1] + rs[2] + rs[3];
    float SS = rss[0] + rss[1] + rss[2] + rss[3];
    float mu = S * (1.f / 512.f);
    float var = SS * (1.f / 512.f) - mu * mu;
    float rstd = rsqrtf(var + 1e-5f);
    y[(size_t)pos * 512 + t] = (v0 - mu) * rstd * g[t] + b[t];
    y[(size_t)pos * 512 + t + 256] = (v1 - mu) * rstd * g[t + 256] + b[t + 256];
}

// ---------------- neighborhood attention: one wave per (pos, head) ----------------
__global__ __launch_bounds__(256) void natt_k(
    const float* __restrict__ qkv, float* __restrict__ o)
{
    int unit = blockIdx.x * 4 + (threadIdx.x >> 6);
    int lane = threadIdx.x & 63;
    int head = unit & 7;
    int pos = unit >> 3;
    int w = pos & 63, h = (pos >> 6) & 31, d = pos >> 11;
    float q = qkv[(size_t)pos * 1536 + head * 64 + lane] * 0.125f;
    float m = -1e30f, l = 0.f, oa = 0.f;
    for (int dz = -2; dz <= 2; dz++) {
        int zz = d + dz;
        if ((unsigned)zz >= 4u) continue;
        for (int dy = -3; dy <= 3; dy++) {
            int yy = h + dy;
            if ((unsigned)yy >= 32u) continue;
            int rb = (zz * 32 + yy) * 64;
            for (int dx = -3; dx <= 3; dx++) {
                int xx = w + dx;
                if ((unsigned)xx >= 64u) continue;
                size_t nb = (size_t)(rb + xx) * 1536 + 512 + head * 64 + lane;
                float t = q * qkv[nb];
#pragma unroll
                for (int off = 32; off; off >>= 1) t += __shfl_xor(t, off);
                float mn = fmaxf(m, t);
                float al = __expf(m - mn);
                float p = __expf(t - mn);
                l = l * al + p;
                oa = fmaf(p, qkv[nb + 512], oa * al);
                m = mn;
            }
        }
    }
    o[(size_t)pos * 512 + head * 64 + lane] = oa / l;
}

// ---------------- residual: lat[c,pos] += ptmp[pos,c] ----------------
__global__ __launch_bounds__(256) void resid_k(float* __restrict__ lat, const float* __restrict__ ptmp)
{
    int idx = blockIdx.x * 256 + threadIdx.x;
    int c = idx >> 13;
    int pos = idx & 8191;
    lat[idx] += ptmp[(size_t)pos * 512 + c];
}

// ---------------- final copy fp32 -> fp32 out ----------------
__global__ __launch_bounds__(256) void copy_k(const float* __restrict__ lat, float* __restrict__ out)
{
    int idx = blockIdx.x * 256 + threadIdx.x;
    out[idx] = lat[idx];
}

extern "C" void kernel_launch(void* const* d_in, const int* in_sizes, int n_in,
                              void* d_out, int out_size, void* d_ws, size_t ws_size,
                              hipStream_t stream)
{
    const float* x2d = (const float*)d_in[0];
    const float* x3d = (const float*)d_in[1];
    const float* sw0 = (const float*)d_in[2];
    const float* sb0 = (const float*)d_in[3];
    const float* sw1 = (const float*)d_in[4];
    const float* sb1 = (const float*)d_in[5];
    const float* sw2 = (const float*)d_in[6];
    const float* sb2 = (const float*)d_in[7];
    const float* pw0 = (const float*)d_in[8];
    const float* pb0 = (const float*)d_in[9];
    const float* pw1 = (const float*)d_in[10];
    const float* pb1 = (const float*)d_in[11];
    const float* pw2 = (const float*)d_in[12];
    const float* pb2 = (const float*)d_in[13];
    const float* latw = (const float*)d_in[14];
    const float* latb = (const float*)d_in[15];
    const float* lng = (const float*)d_in[16];
    const float* lnb = (const float*)d_in[17];
    const float* qkvw = (const float*)d_in[18];
    const float* qkvb = (const float*)d_in[19];
    const float* projw = (const float*)d_in[20];
    const float* projb = (const float*)d_in[21];
    float* outp = (float*)d_out;

    char* ws = (char*)d_ws;
    size_t off_p0 = 0;
    size_t off_p1 = off_p0 + 100663296ull;
    size_t off_p2 = off_p1 + 25165824ull;
    size_t off_s2 = off_p2 + 12582912ull;
    size_t off_ft = off_s2 + 4194304ull;
    size_t off_lat = off_ft + 16777216ull;

    bf16* s0 = (bf16*)(ws + off_p1);
    bf16* s1 = (bf16*)(ws + off_p2);
    float* s2 = (float*)(ws + off_s2);
    bf16* p0 = (bf16*)(ws + off_p0);
    bf16* p1 = (bf16*)(ws + off_p1);
    float* p2 = (float*)(ws + off_p2);
    float* feats = (float*)(ws + off_ft);
    float* lat = (float*)(ws + off_lat);
    float* qkv = (float*)(ws + off_p0);
    float* y = (float*)(ws + off_p0 + 50331648ull);
    float* attno = (float*)(ws + off_p0 + 67108864ull);
    float* ptmp = (float*)(ws + off_p0 + 83886080ull);

    // surface path: [8,256,512] -> [128,128,256] -> [256,64,128] -> [512,32,64]
    conv2d_t<float, bf16, 8, 8><<<dim3(8, 16, 4), 256, 0, stream>>>(x2d, sw0, sb0, s0, 256, 512, 128, 256);
    conv2d_t<bf16, bf16, 128, 8><<<dim3(4, 8, 8), 256, 0, stream>>>(s0, sw1, sb1, s1, 128, 256, 64, 128);
    conv2d_t<bf16, float, 256, 8><<<dim3(2, 4, 16), 256, 0, stream>>>(s1, sw2, sb2, s2, 64, 128, 32, 64);

    // pressure path: [5,24,256,512] -> [128,12,128,256] -> [256,6,64,128] -> [512,3,32,64]
    conv3d_t<float, bf16, 5, 5><<<dim3(8, 384, 2), 256, 0, stream>>>(x3d, pw0, pb0, p0, 24, 256, 512, 12, 128, 256, 32);
    conv3d_t<bf16, bf16, 128, 4><<<dim3(4, 96, 4), 256, 0, stream>>>(p0, pw1, pb1, p1, 12, 128, 256, 6, 64, 128, 16);
    conv3d_t<bf16, float, 256, 4><<<dim3(2, 24, 8), 256, 0, stream>>>(p1, pw2, pb2, p2, 6, 64, 128, 3, 32, 64, 8);

    // concat + lateral 1x1x1 conv (GEMM [512,512] x [512,8192])
    concat_k<<<16384, 256, 0, stream>>>(p2, s2, feats);
    gemm_k<<<dim3(128, 8), 256, 0, stream>>>(latw, feats, latb, lat, 512, 8192, 512, 2);

    // 3 rounds of neighborhood attention
    for (int r = 0; r < 3; r++) {
        ln_k<<<8192, 256, 0, stream>>>(lat, lng + r * 512, lnb + r * 512, y, 8192);
        gemm_k<<<dim3(24, 128), 256, 0, stream>>>(
            y, qkvw + (size_t)r * 512 * 1536, qkvb + r * 1536, qkv, 8192, 1536, 512, 1);
        natt_k<<<16384, 256, 0, stream>>>(qkv, attno);
        gemm_k<<<dim3(8, 128), 256, 0, stream>>>(
            attno, projw + (size_t)r * 512 * 512, projb + r * 512, ptmp, 8192, 512, 512, 1);
        resid_k<<<16384, 256, 0, stream>>>(lat, ptmp);
    }

    copy_k<<<16384, 256, 0, stream>>>(lat, outp);
}

// Round 4
// 3752.277 us; speedup vs baseline: 13.2237x; 2.7525x over previous
//
#include <hip/hip_runtime.h>
#include <hip/hip_bf16.h>
#include <math.h>

typedef __hip_bfloat16 bf16;
typedef __attribute__((ext_vector_type(8))) short s8v;
typedef __attribute__((ext_vector_type(4))) float f4v;

__device__ __forceinline__ float ldf(const float* p) { return *p; }
__device__ __forceinline__ float ldf(const bf16* p) { return __bfloat162float(*p); }
__device__ __forceinline__ void stf(float* p, float v) { *p = v; }
__device__ __forceinline__ void stf(bf16* p, float v) { *p = __float2bfloat16(v); }

__device__ __forceinline__ float gelu_tanh(float x) {
    float x3 = x * x * x;
    return 0.5f * x * (1.f + tanhf(0.7978845608028654f * (x + 0.044715f * x3)));
}
__device__ __forceinline__ unsigned short bfbits(float x) {
    bf16 t = __float2bfloat16(x);
    return *(unsigned short*)&t;
}

// ---------------- zero fill (16B granules) ----------------
__global__ __launch_bounds__(256) void fill0_k(uint4* __restrict__ p, int n16)
{
    int i = blockIdx.x * 256 + threadIdx.x;
    if (i < n16) p[i] = uint4{0u, 0u, 0u, 0u};
}

// ---------------- weight reorder: fp32 [OC][IC][T] -> bf16 [T][OC][IC] ----------------
__global__ __launch_bounds__(256) void wprep_k(const float* __restrict__ w, bf16* __restrict__ wr,
                                               int OC, int IC, int T)
{
    int i = blockIdx.x * 256 + threadIdx.x;
    if (i >= OC * IC * T) return;
    int t = i % T; int rem = i / T; int ic = rem % IC; int oc = rem / IC;
    wr[((size_t)t * OC + oc) * IC + ic] = __float2bfloat16(w[i]);
}

// ---------------- transpose cast: fp32 [K][N] -> bf16 [N][K] ----------------
__global__ __launch_bounds__(256) void tprep_k(const float* __restrict__ w, bf16* __restrict__ wt,
                                               int K, int N)
{
    int i = blockIdx.x * 256 + threadIdx.x;
    if (i >= K * N) return;
    int n = i % N, k = i / N;
    wt[(size_t)n * K + k] = __float2bfloat16(w[i]);
}

// ---------------- plain cast fp32 -> bf16 ----------------
__global__ __launch_bounds__(256) void cast_k(const float* __restrict__ w, bf16* __restrict__ o, int n)
{
    int i = blockIdx.x * 256 + threadIdx.x;
    if (i < n) o[i] = __float2bfloat16(w[i]);
}

// ================= VALU conv3d #1 (IC=5): planar fp32 in -> NHWC x-padded bf16 out =================
template <typename TIn, int IC, int ICB>
__global__ __launch_bounds__(256) void conv3d_v(
    const TIn* __restrict__ in, const float* __restrict__ w, const float* __restrict__ bias,
    bf16* __restrict__ out, int ID, int IH, int IW, int OD, int OH, int OW, int OHB,
    int OWS, int OCt)
{
    constexpr int XT = 65, YT = 9, ZT = 3, WS = 68;
    constexpr int NX = ICB * ZT * YT * XT;
    constexpr int NTAP = ICB * 27;
    __shared__ float xs[NX];
    __shared__ float wsh[NTAP * WS];
    int tid = threadIdx.x;
    int bx = blockIdx.x, by = blockIdx.y;
    int oc0 = blockIdx.z * 64;
    int od = by / OHB, ohb = by - od * OHB;
    int oh0 = ohb * 4;
    int owl = tid & 31, ohl = (tid >> 5) & 3, half = tid >> 7;
    int ix0 = bx * 64 - 1, iy0 = oh0 * 2 - 1, iz0 = od * 2 - 1;
    float acc[32];
#pragma unroll
    for (int j = 0; j < 32; j++) acc[j] = bias[oc0 + half * 32 + j];

    for (int ic0 = 0; ic0 < IC; ic0 += ICB) {
        __syncthreads();
        for (int i = tid; i < NX; i += 256) {
            int icl = i / (ZT * YT * XT);
            int r = i - icl * (ZT * YT * XT);
            int zz = r / (YT * XT);
            int r2 = r - zz * (YT * XT);
            int yy = r2 / XT;
            int xx = r2 - yy * XT;
            int iz = iz0 + zz, iy = iy0 + yy, ix = ix0 + xx;
            float v = 0.f;
            if ((unsigned)iz < (unsigned)ID && (unsigned)iy < (unsigned)IH && (unsigned)ix < (unsigned)IW)
                v = ldf(&in[(((size_t)(ic0 + icl) * ID + iz) * IH + iy) * IW + ix]);
            xs[i] = v;
        }
        for (int i = tid; i < 64 * NTAP; i += 256) {
            int ocl = i / NTAP;
            int t = i - ocl * NTAP;
            wsh[t * WS + ocl] = w[((size_t)(oc0 + ocl) * IC + ic0) * 27 + t];
        }
        __syncthreads();
#pragma unroll 1
        for (int icl = 0; icl < ICB; icl++) {
#pragma unroll
            for (int kz = 0; kz < 3; kz++) {
#pragma unroll
                for (int ky = 0; ky < 3; ky++) {
                    int xb = ((icl * ZT + kz) * YT + (2 * ohl + ky)) * XT + 2 * owl;
#pragma unroll
                    for (int kx = 0; kx < 3; kx++) {
                        float xv = xs[xb + kx];
                        const float4* wr = (const float4*)&wsh[(icl * 27 + kz * 9 + ky * 3 + kx) * WS + half * 32];
#pragma unroll
                        for (int j4 = 0; j4 < 8; j4++) {
                            float4 wv = wr[j4];
                            acc[j4 * 4 + 0] = fmaf(xv, wv.x, acc[j4 * 4 + 0]);
                            acc[j4 * 4 + 1] = fmaf(xv, wv.y, acc[j4 * 4 + 1]);
                            acc[j4 * 4 + 2] = fmaf(xv, wv.z, acc[j4 * 4 + 2]);
                            acc[j4 * 4 + 3] = fmaf(xv, wv.w, acc[j4 * 4 + 3]);
                        }
                    }
                }
            }
        }
    }
    int ow = bx * 32 + owl, oh = oh0 + ohl;
    size_t base = (((size_t)od * OH + oh) * OWS + ow + 1) * OCt + oc0 + half * 32;
#pragma unroll
    for (int j = 0; j < 32; j++) out[base + j] = __float2bfloat16(gelu_tanh(acc[j]));
}

// ================= VALU conv2d #1 (IC=8): planar fp32 in -> NHWC x-padded bf16 out =================
template <typename TIn, int IC, int ICB>
__global__ __launch_bounds__(256) void conv2d_v(
    const TIn* __restrict__ in, const float* __restrict__ w, const float* __restrict__ bias,
    bf16* __restrict__ out, int IH, int IW, int OH, int OW, int OWS, int OCt)
{
    constexpr int XT = 65, YT = 17, WS = 36;
    constexpr int NX = ICB * YT * XT;
    constexpr int NTAP = ICB * 9;
    __shared__ float xs[NX];
    __shared__ float wsh[NTAP * WS];
    int tid = threadIdx.x;
    int bx = blockIdx.x, by = blockIdx.y;
    int oc0 = blockIdx.z * 32;
    int oh0 = by * 8;
    int owl = tid & 31, ohl = tid >> 5;
    int ix0 = bx * 64 - 1, iy0 = oh0 * 2 - 1;
    float acc[32];
#pragma unroll
    for (int j = 0; j < 32; j++) acc[j] = bias[oc0 + j];

    for (int ic0 = 0; ic0 < IC; ic0 += ICB) {
        __syncthreads();
        for (int i = tid; i < NX; i += 256) {
            int icl = i / (YT * XT);
            int r = i - icl * (YT * XT);
            int yy = r / XT;
            int xx = r - yy * XT;
            int iy = iy0 + yy, ix = ix0 + xx;
            float v = 0.f;
            if ((unsigned)iy < (unsigned)IH && (unsigned)ix < (unsigned)IW)
                v = ldf(&in[((size_t)(ic0 + icl) * IH + iy) * IW + ix]);
            xs[i] = v;
        }
        for (int i = tid; i < 32 * NTAP; i += 256) {
            int ocl = i / NTAP;
            int t = i - ocl * NTAP;
            wsh[t * WS + ocl] = w[((size_t)(oc0 + ocl) * IC + ic0) * 9 + t];
        }
        __syncthreads();
#pragma unroll 1
        for (int icl = 0; icl < ICB; icl++) {
#pragma unroll
            for (int ky = 0; ky < 3; ky++) {
                int xb = (icl * YT + (2 * ohl + ky)) * XT + 2 * owl;
#pragma unroll
                for (int kx = 0; kx < 3; kx++) {
                    float xv = xs[xb + kx];
                    const float4* wr = (const float4*)&wsh[(icl * 9 + ky * 3 + kx) * WS];
#pragma unroll
                    for (int j4 = 0; j4 < 8; j4++) {
                        float4 wv = wr[j4];
                        acc[j4 * 4 + 0] = fmaf(xv, wv.x, acc[j4 * 4 + 0]);
                        acc[j4 * 4 + 1] = fmaf(xv, wv.y, acc[j4 * 4 + 1]);
                        acc[j4 * 4 + 2] = fmaf(xv, wv.z, acc[j4 * 4 + 2]);
                        acc[j4 * 4 + 3] = fmaf(xv, wv.w, acc[j4 * 4 + 3]);
                    }
                }
            }
        }
    }
    int ow = bx * 32 + owl, oh = oh0 + ohl;
    size_t base = ((size_t)oh * OWS + ow + 1) * OCt + oc0;
#pragma unroll
    for (int j = 0; j < 32; j++) out[base + j] = __float2bfloat16(gelu_tanh(acc[j]));
}

// ================= MFMA tap-GEMM conv (#2/#3, 2d/3d): NHWC bf16 -> NHWC bf16 + GELU =================
// Block = one output x-row (od,oh fixed): BM == OW. N-tile = 128 ocs.
// Grid: (OC/128, OD*OH). K = taps x IC, block-uniform tap skip at z/y boundaries.
template <int BM, int KD>
__global__ __launch_bounds__(256) void conv_mfma(
    const bf16* __restrict__ in, const bf16* __restrict__ wr, const float* __restrict__ bias,
    bf16* __restrict__ out, int ID, int IH, int IWp, int IC,
    int OH, int OC, int OWS, int outPad)
{
    constexpr int NI = (BM == 128) ? 4 : 2;
    __shared__ __align__(16) bf16 As[BM * 32];
    __shared__ __align__(16) bf16 Bs[128 * 32];
    int tid = threadIdx.x;
    int n0 = blockIdx.x * 128;
    int rowid = blockIdx.y;
    int od = rowid / OH, oh = rowid % OH;
    int wave = tid >> 6, lane = tid & 63;
    int wm = (BM == 128) ? (wave >> 1) * 64 : 0;
    int wn = (BM == 128) ? (wave & 1) * 64 : wave * 32;
    int lm = lane & 15, lq = lane >> 4;
    f4v acc[4][NI];
#pragma unroll
    for (int i = 0; i < 4; i++)
#pragma unroll
        for (int j = 0; j < NI; j++) acc[i][j] = f4v{0.f, 0.f, 0.f, 0.f};

    int arow, asub;
    if (BM == 128) { arow = tid >> 1; asub = (tid & 1) * 16; }
    else           { arow = tid >> 2; asub = (tid & 3) * 8; }
    int brow = tid >> 1, bsub = (tid & 1) * 16;

    for (int kz = 0; kz < KD; kz++) {
        int iz = (KD == 3) ? (2 * od + kz - 1) : 0;
        if ((unsigned)iz >= (unsigned)ID) continue;
        for (int ky = 0; ky < 3; ky++) {
            int iy = 2 * oh + ky - 1;
            if ((unsigned)iy >= (unsigned)IH) continue;
            const bf16* inrow = in + ((size_t)iz * IH + iy) * IWp * IC;
            for (int kx = 0; kx < 3; kx++) {
                int tap = (kz * 3 + ky) * 3 + kx;
                const bf16* wtap = wr + (size_t)tap * OC * IC;
                for (int kb = 0; kb < IC; kb += 32) {
                    __syncthreads();
                    {
                        const uint4* g = (const uint4*)&inrow[(size_t)(2 * arow + kx) * IC + kb + asub];
                        uint4* l = (uint4*)&As[arow * 32 + asub];
                        if (BM == 128) { l[0] = g[0]; l[1] = g[1]; }
                        else           { l[0] = g[0]; }
                    }
                    {
                        const uint4* g = (const uint4*)&wtap[(size_t)(n0 + brow) * IC + kb + bsub];
                        uint4* l = (uint4*)&Bs[brow * 32 + bsub];
                        l[0] = g[0]; l[1] = g[1];
                    }
                    __syncthreads();
                    s8v af[4], bfr[NI];
#pragma unroll
                    for (int mi = 0; mi < 4; mi++) af[mi] = *(const s8v*)&As[(wm + mi * 16 + lm) * 32 + lq * 8];
#pragma unroll
                    for (int ni = 0; ni < NI; ni++) bfr[ni] = *(const s8v*)&Bs[(wn + ni * 16 + lm) * 32 + lq * 8];
#pragma unroll
                    for (int mi = 0; mi < 4; mi++)
#pragma unroll
                        for (int ni = 0; ni < NI; ni++)
                            acc[mi][ni] = __builtin_amdgcn_mfma_f32_16x16x32_bf16(af[mi], bfr[ni], acc[mi][ni], 0, 0, 0);
                }
            }
        }
    }
    size_t orowbase = ((size_t)rowid * OWS + outPad) * OC;
#pragma unroll
    for (int mi = 0; mi < 4; mi++)
#pragma unroll
        for (int ni = 0; ni < NI; ni++)
#pragma unroll
            for (int r = 0; r < 4; r++) {
                int m = wm + mi * 16 + lq * 4 + r;
                int n = n0 + wn + ni * 16 + lm;
                float v = acc[mi][ni][r] + bias[n];
                out[orowbase + (size_t)m * OC + n] = __float2bfloat16(gelu_tanh(v));
            }
}

// ================= MFMA GEMM: C[M,N] = A[M,K] * Bt[N,K]^T + bias (+res) =================
// 128x128 tile, BK=32, 4 waves of 64x64. A,Bt bf16 k-contiguous.
template <typename OutT, int RES>
__global__ __launch_bounds__(256) void gemm_bt(
    const bf16* __restrict__ A, const bf16* __restrict__ Bt, const float* __restrict__ bias,
    OutT* __restrict__ C, const float* __restrict__ res, int M, int N, int K)
{
    __shared__ __align__(16) bf16 As[128 * 32];
    __shared__ __align__(16) bf16 Bs[128 * 32];
    int tid = threadIdx.x;
    int n0 = blockIdx.x * 128, m0 = blockIdx.y * 128;
    int wave = tid >> 6, lane = tid & 63;
    int wm = (wave >> 1) * 64, wn = (wave & 1) * 64;
    int lm = lane & 15, lq = lane >> 4;
    f4v acc[4][4];
#pragma unroll
    for (int i = 0; i < 4; i++)
#pragma unroll
        for (int j = 0; j < 4; j++) acc[i][j] = f4v{0.f, 0.f, 0.f, 0.f};
    int srow = tid >> 1, ssub = (tid & 1) * 16;
    for (int k0 = 0; k0 < K; k0 += 32) {
        __syncthreads();
        {
            const uint4* g = (const uint4*)&A[(size_t)(m0 + srow) * K + k0 + ssub];
            uint4* l = (uint4*)&As[srow * 32 + ssub];
            l[0] = g[0]; l[1] = g[1];
        }
        {
            const uint4* g = (const uint4*)&Bt[(size_t)(n0 + srow) * K + k0 + ssub];
            uint4* l = (uint4*)&Bs[srow * 32 + ssub];
            l[0] = g[0]; l[1] = g[1];
        }
        __syncthreads();
        s8v af[4], bfr[4];
#pragma unroll
        for (int mi = 0; mi < 4; mi++) af[mi] = *(const s8v*)&As[(wm + mi * 16 + lm) * 32 + lq * 8];
#pragma unroll
        for (int ni = 0; ni < 4; ni++) bfr[ni] = *(const s8v*)&Bs[(wn + ni * 16 + lm) * 32 + lq * 8];
#pragma unroll
        for (int mi = 0; mi < 4; mi++)
#pragma unroll
            for (int ni = 0; ni < 4; ni++)
                acc[mi][ni] = __builtin_amdgcn_mfma_f32_16x16x32_bf16(af[mi], bfr[ni], acc[mi][ni], 0, 0, 0);
    }
#pragma unroll
    for (int mi = 0; mi < 4; mi++)
#pragma unroll
        for (int ni = 0; ni < 4; ni++)
#pragma unroll
            for (int r = 0; r < 4; r++) {
                int m = m0 + wm + mi * 16 + lq * 4 + r;
                int n = n0 + wn + ni * 16 + lm;
                float v = acc[mi][ni][r] + bias[n];
                if (RES) v += res[(size_t)m * N + n];
                stf(&C[(size_t)m * N + n], v);
            }
}

// ---------------- LayerNorm: lat fp32 [P,512] -> y bf16 [P,512]; one wave per token ----------------
__global__ __launch_bounds__(256) void ln_k(
    const float* __restrict__ lat, const float* __restrict__ g, const float* __restrict__ b,
    bf16* __restrict__ y)
{
    int tok = blockIdx.x * 4 + (threadIdx.x >> 6);
    int lane = threadIdx.x & 63;
    const float4* row = (const float4*)&lat[(size_t)tok * 512 + lane * 8];
    float4 a = row[0], c = row[1];
    float s = a.x + a.y + a.z + a.w + c.x + c.y + c.z + c.w;
    float ss = a.x * a.x + a.y * a.y + a.z * a.z + a.w * a.w
             + c.x * c.x + c.y * c.y + c.z * c.z + c.w * c.w;
#pragma unroll
    for (int off = 32; off; off >>= 1) {
        s += __shfl_xor(s, off);
        ss += __shfl_xor(ss, off);
    }
    float mu = s * (1.f / 512.f);
    float var = ss * (1.f / 512.f) - mu * mu;
    float rstd = rsqrtf(var + 1e-5f);
    const float4* gp = (const float4*)&g[lane * 8];
    const float4* bp = (const float4*)&b[lane * 8];
    float4 g0 = gp[0], g1 = gp[1], b0 = bp[0], b1 = bp[1];
    union { uint4 u; unsigned short h[8]; } pk;
    pk.h[0] = bfbits((a.x - mu) * rstd * g0.x + b0.x);
    pk.h[1] = bfbits((a.y - mu) * rstd * g0.y + b0.y);
    pk.h[2] = bfbits((a.z - mu) * rstd * g0.z + b0.z);
    pk.h[3] = bfbits((a.w - mu) * rstd * g0.w + b0.w);
    pk.h[4] = bfbits((c.x - mu) * rstd * g1.x + b1.x);
    pk.h[5] = bfbits((c.y - mu) * rstd * g1.y + b1.y);
    pk.h[6] = bfbits((c.z - mu) * rstd * g1.z + b1.z);
    pk.h[7] = bfbits((c.w - mu) * rstd * g1.w + b1.w);
    *(uint4*)&y[(size_t)tok * 512 + lane * 8] = pk.u;
}

// ---------------- neighborhood attention: one wave per (pos, head); qkv bf16 [P,1536] ----------------
__global__ __launch_bounds__(256) void natt_k(
    const bf16* __restrict__ qkv, bf16* __restrict__ o)
{
    int unit = blockIdx.x * 4 + (threadIdx.x >> 6);
    int lane = threadIdx.x & 63;
    int head = unit & 7;
    int pos = unit >> 3;
    int w = pos & 63, h = (pos >> 6) & 31, d = pos >> 11;
    float q = ldf(&qkv[(size_t)pos * 1536 + head * 64 + lane]) * 0.125f;
    float m = -1e30f, l = 0.f, oa = 0.f;
    for (int dz = -2; dz <= 2; dz++) {
        int zz = d + dz;
        if ((unsigned)zz >= 4u) continue;
        for (int dy = -3; dy <= 3; dy++) {
            int yy = h + dy;
            if ((unsigned)yy >= 32u) continue;
            int rb = (zz * 32 + yy) * 64;
            for (int dx = -3; dx <= 3; dx++) {
                int xx = w + dx;
                if ((unsigned)xx >= 64u) continue;
                size_t nb = (size_t)(rb + xx) * 1536 + 512 + head * 64 + lane;
                float t = q * ldf(&qkv[nb]);
#pragma unroll
                for (int off = 32; off; off >>= 1) t += __shfl_xor(t, off);
                float mn = fmaxf(m, t);
                float al = __expf(m - mn);
                float p = __expf(t - mn);
                l = l * al + p;
                oa = fmaf(p, ldf(&qkv[nb + 512]), oa * al);
                m = mn;
            }
        }
    }
    o[(size_t)pos * 512 + head * 64 + lane] = __float2bfloat16(oa / l);
}

// ---------------- final transpose: lat [P,512] fp32 -> out planar [512,P] ----------------
__global__ __launch_bounds__(256) void tout_k(const float* __restrict__ lat, float* __restrict__ out)
{
    __shared__ float t[64][65];
    int p0 = blockIdx.x * 64, c0 = blockIdx.y * 64;
    for (int i = threadIdx.x; i < 4096; i += 256) {
        int r = i >> 6, cc = i & 63;
        t[r][cc] = lat[(size_t)(p0 + r) * 512 + c0 + cc];
    }
    __syncthreads();
    for (int i = threadIdx.x; i < 4096; i += 256) {
        int cc = i >> 6, r = i & 63;
        out[(size_t)(c0 + cc) * 8192 + p0 + r] = t[r][cc];
    }
}

extern "C" void kernel_launch(void* const* d_in, const int* in_sizes, int n_in,
                              void* d_out, int out_size, void* d_ws, size_t ws_size,
                              hipStream_t stream)
{
    const float* x2d = (const float*)d_in[0];
    const float* x3d = (const float*)d_in[1];
    const float* sw0 = (const float*)d_in[2];
    const float* sb0 = (const float*)d_in[3];
    const float* sw1 = (const float*)d_in[4];
    const float* sb1 = (const float*)d_in[5];
    const float* sw2 = (const float*)d_in[6];
    const float* sb2 = (const float*)d_in[7];
    const float* pw0 = (const float*)d_in[8];
    const float* pb0 = (const float*)d_in[9];
    const float* pw1 = (const float*)d_in[10];
    const float* pb1 = (const float*)d_in[11];
    const float* pw2 = (const float*)d_in[12];
    const float* pb2 = (const float*)d_in[13];
    const float* latw = (const float*)d_in[14];
    const float* latb = (const float*)d_in[15];
    const float* lng = (const float*)d_in[16];
    const float* lnb = (const float*)d_in[17];
    const float* qkvw = (const float*)d_in[18];
    const float* qkvb = (const float*)d_in[19];
    const float* projw = (const float*)d_in[20];
    const float* projb = (const float*)d_in[21];
    float* outp = (float*)d_out;

    char* ws = (char*)d_ws;
    // layout (bytes), all 16B-aligned:
    bf16* p0pad  = (bf16*)(ws + 0);            // [12][128][258][128] = 101,449,728
    bf16* p1pad  = (bf16*)(ws + 101449728ull); // [6][64][130][256]   =  25,559,040
    bf16* s0pad  = (bf16*)(ws + 127008768ull); // [128][258][128]     =   8,454,144
    bf16* s1pad  = (bf16*)(ws + 135462912ull); // [64][130][256]      =   4,259,840
    bf16* featsT = (bf16*)(ws + 139722752ull); // [8192][512] bf16    =   8,388,608
    float* lat   = (float*)(ws + 148111360ull);// [8192][512] fp32    =  16,777,216
    bf16* wr3d2  = (bf16*)(ws + 164888576ull); // 27*256*128
    bf16* wr3d3  = (bf16*)(ws + 166658048ull); // 27*512*256
    bf16* wr2d2  = (bf16*)(ws + 173735936ull); // 9*256*128
    bf16* wr2d3  = (bf16*)(ws + 174325760ull); // 9*512*256
    bf16* qkvt   = (bf16*)(ws + 176685056ull); // 3*1536*512
    bf16* projt  = (bf16*)(ws + 181403648ull); // 3*512*512
    bf16* latbf  = (bf16*)(ws + 182976512ull); // 512*512
    // attention-phase aliases into dead p0pad region:
    bf16* ybf    = (bf16*)(ws + 0);            // 8,388,608
    bf16* qkvbuf = (bf16*)(ws + 8388608ull);   // 25,165,824
    bf16* attno  = (bf16*)(ws + 33554432ull);  // 8,388,608

    // 1) zero conv buffers (p0..s1 contiguous = 139,722,752 B = 8,732,672 x16B)
    fill0_k<<<34112, 256, 0, stream>>>((uint4*)ws, 8732672);

    // 2) weight prep
    wprep_k<<<3456, 256, 0, stream>>>(pw1, wr3d2, 256, 128, 27);
    wprep_k<<<13824, 256, 0, stream>>>(pw2, wr3d3, 512, 256, 27);
    wprep_k<<<1152, 256, 0, stream>>>(sw1, wr2d2, 256, 128, 9);
    wprep_k<<<4608, 256, 0, stream>>>(sw2, wr2d3, 512, 256, 9);
    for (int r = 0; r < 3; r++) {
        tprep_k<<<3072, 256, 0, stream>>>(qkvw + (size_t)r * 786432, qkvt + (size_t)r * 786432, 512, 1536);
        tprep_k<<<1024, 256, 0, stream>>>(projw + (size_t)r * 262144, projt + (size_t)r * 262144, 512, 512);
    }
    cast_k<<<1024, 256, 0, stream>>>(latw, latbf, 262144);

    // 3) conv chains
    conv2d_v<float, 8, 8><<<dim3(8, 16, 4), 256, 0, stream>>>(x2d, sw0, sb0, s0pad, 256, 512, 128, 256, 258, 128);
    conv_mfma<128, 1><<<dim3(2, 64), 256, 0, stream>>>(s0pad, wr2d2, sb1, s1pad, 1, 128, 258, 128, 64, 256, 130, 1);
    conv_mfma<64, 1><<<dim3(4, 32), 256, 0, stream>>>(s1pad, wr2d3, sb2, featsT + (size_t)6144 * 512, 1, 64, 130, 256, 32, 512, 64, 0);

    conv3d_v<float, 5, 5><<<dim3(8, 384, 2), 256, 0, stream>>>(x3d, pw0, pb0, p0pad, 24, 256, 512, 12, 128, 256, 32, 258, 128);
    conv_mfma<128, 3><<<dim3(2, 384), 256, 0, stream>>>(p0pad, wr3d2, pb1, p1pad, 12, 128, 258, 128, 64, 256, 130, 1);
    conv_mfma<64, 3><<<dim3(4, 96), 256, 0, stream>>>(p1pad, wr3d3, pb2, featsT, 6, 64, 130, 256, 32, 512, 64, 0);

    // 4) lateral 1x1 conv: lat[pos][oc] = featsT . latw^T + latb
    gemm_bt<float, 0><<<dim3(4, 64), 256, 0, stream>>>(featsT, latbf, latb, lat, nullptr, 8192, 512, 512);

    // 5) 3 attention rounds
    for (int r = 0; r < 3; r++) {
        ln_k<<<2048, 256, 0, stream>>>(lat, lng + r * 512, lnb + r * 512, ybf);
        gemm_bt<bf16, 0><<<dim3(12, 64), 256, 0, stream>>>(ybf, qkvt + (size_t)r * 786432, qkvb + r * 1536,
                                                           qkvbuf, nullptr, 8192, 1536, 512);
        natt_k<<<16384, 256, 0, stream>>>(qkvbuf, attno);
        gemm_bt<float, 1><<<dim3(4, 64), 256, 0, stream>>>(attno, projt + (size_t)r * 262144, projb + r * 512,
                                                           lat, lat, 8192, 512, 512);
    }

    // 6) transpose to planar output [512][4][32][64]
    tout_k<<<dim3(128, 8), 256, 0, stream>>>(lat, outp);
}

// Round 5
// 3276.108 us; speedup vs baseline: 15.1458x; 1.1453x over previous
//
#include <hip/hip_runtime.h>
#include <hip/hip_bf16.h>
#include <math.h>

typedef __hip_bfloat16 bf16;
typedef __attribute__((ext_vector_type(8))) short s8v;
typedef __attribute__((ext_vector_type(4))) float f4v;

__device__ __forceinline__ float ldf(const float* p) { return *p; }
__device__ __forceinline__ float ldf(const bf16* p) { return __bfloat162float(*p); }
__device__ __forceinline__ void stf(float* p, float v) { *p = v; }
__device__ __forceinline__ void stf(bf16* p, float v) { *p = __float2bfloat16(v); }

__device__ __forceinline__ float gelu_tanh(float x) {
    float x3 = x * x * x;
    return 0.5f * x * (1.f + tanhf(0.7978845608028654f * (x + 0.044715f * x3)));
}
__device__ __forceinline__ unsigned short bfbits(float x) {
    bf16 t = __float2bfloat16(x);
    return *(unsigned short*)&t;
}

// ---------------- zero fill (16B granules) ----------------
__global__ __launch_bounds__(256) void fill0_k(uint4* __restrict__ p, int n16)
{
    int i = blockIdx.x * 256 + threadIdx.x;
    if (i < n16) p[i] = uint4{0u, 0u, 0u, 0u};
}

// ---------------- weight reorder: fp32 [OC][IC][T] -> bf16 [T][OC][IC] ----------------
__global__ __launch_bounds__(256) void wprep_k(const float* __restrict__ w, bf16* __restrict__ wr,
                                               int OC, int IC, int T)
{
    int i = blockIdx.x * 256 + threadIdx.x;
    if (i >= OC * IC * T) return;
    int t = i % T; int rem = i / T; int ic = rem % IC; int oc = rem / IC;
    wr[((size_t)t * OC + oc) * IC + ic] = __float2bfloat16(w[i]);
}

// ---------------- conv#1 weight prep: fp32 [OC][nic][ntap] -> bf16 [OC][Kp], k=tap*nic+ic ----------------
__global__ __launch_bounds__(256) void w1prep_k(const float* __restrict__ w, bf16* __restrict__ o,
                                                int OC, int nic, int ntap, int Kp)
{
    int i = blockIdx.x * 256 + threadIdx.x;
    if (i >= OC * Kp) return;
    int oc = i / Kp, k = i - oc * Kp;
    float v = 0.f;
    if (k < nic * ntap) {
        int tap = k / nic, ic = k - tap * nic;
        v = w[((size_t)oc * nic + ic) * ntap + tap];
    }
    o[i] = __float2bfloat16(v);
}

// ---------------- transpose cast: fp32 [K][N] -> bf16 [N][K] ----------------
__global__ __launch_bounds__(256) void tprep_k(const float* __restrict__ w, bf16* __restrict__ wt,
                                               int K, int N)
{
    int i = blockIdx.x * 256 + threadIdx.x;
    if (i >= K * N) return;
    int n = i % N, k = i / N;
    wt[(size_t)n * K + k] = __float2bfloat16(w[i]);
}

// ---------------- plain cast fp32 -> bf16 ----------------
__global__ __launch_bounds__(256) void cast_k(const float* __restrict__ w, bf16* __restrict__ o, int n)
{
    int i = blockIdx.x * 256 + threadIdx.x;
    if (i < n) o[i] = __float2bfloat16(w[i]);
}

// ---------------- im2col for conv3d#1: x3d fp32 [5][24][256][512] -> A bf16 [196608][160] ----------------
// k = tap*5 + ic, tap = (kz*3+ky)*3+kx; covers od in [od0, od0+6)
__global__ __launch_bounds__(256) void im2col3d_k(const float* __restrict__ x, bf16* __restrict__ A, int od0)
{
    int gid = blockIdx.x * 256 + threadIdx.x;  // 196608*20
    int m = gid / 20, kg = gid - 20 * (gid / 20);
    int ow = m & 255, rowid = m >> 8;
    int oh = rowid & 127, od = od0 + (rowid >> 7);
    int iz0 = 2 * od - 1, iy0 = 2 * oh - 1, ix0 = 2 * ow - 1;
    union { uint4 u; unsigned short h[8]; } pk;
#pragma unroll
    for (int j = 0; j < 8; j++) {
        int k = kg * 8 + j;
        float v = 0.f;
        if (k < 135) {
            int tap = k / 5, ic = k - tap * 5;
            int kz = tap / 9, r = tap - kz * 9;
            int ky = r / 3, kx = r - ky * 3;
            int iz = iz0 + kz, iy = iy0 + ky, ix = ix0 + kx;
            if ((unsigned)iz < 24u && (unsigned)iy < 256u && (unsigned)ix < 512u)
                v = x[(((size_t)ic * 24 + iz) * 256 + iy) * 512 + ix];
        }
        pk.h[j] = bfbits(v);
    }
    *(uint4*)&A[(size_t)m * 160 + kg * 8] = pk.u;
}

// ---------------- im2col for conv2d#1: x2d fp32 [8][256][512] -> A bf16 [32768][96] ----------------
__global__ __launch_bounds__(256) void im2col2d_k(const float* __restrict__ x, bf16* __restrict__ A)
{
    int gid = blockIdx.x * 256 + threadIdx.x;  // 32768*12
    int m = gid / 12, kg = gid - 12 * (gid / 12);
    int ow = m & 255, oh = m >> 8;
    int iy0 = 2 * oh - 1, ix0 = 2 * ow - 1;
    union { uint4 u; unsigned short h[8]; } pk;
#pragma unroll
    for (int j = 0; j < 8; j++) {
        int k = kg * 8 + j;
        float v = 0.f;
        if (k < 72) {
            int tap = k >> 3, ic = k & 7;
            int ky = tap / 3, kx = tap - ky * 3;
            int iy = iy0 + ky, ix = ix0 + kx;
            if ((unsigned)iy < 256u && (unsigned)ix < 512u)
                v = x[((size_t)ic * 256 + iy) * 512 + ix];
        }
        pk.h[j] = bfbits(v);
    }
    *(uint4*)&A[(size_t)m * 96 + kg * 8] = pk.u;
}

// ---------------- conv#1 GEMM: C = A[M][Kp] x W[128][Kp]^T, +bias, GELU, padded NHWC store ----------------
// N=128 fixed, OW=256 (m = row*256 + x), OWS=258, OC=128. grid (M/128).
__global__ __launch_bounds__(256) void conv1_gemm(
    const bf16* __restrict__ A, const bf16* __restrict__ W, const float* __restrict__ bias,
    bf16* __restrict__ out, int M, int Kp, int rowOff)
{
    __shared__ __align__(16) bf16 As[128 * 32];
    __shared__ __align__(16) bf16 Bs[128 * 32];
    int tid = threadIdx.x;
    int m0 = blockIdx.x * 128;
    int wave = tid >> 6, lane = tid & 63;
    int wm = (wave >> 1) * 64, wn = (wave & 1) * 64;
    int lm = lane & 15, lq = lane >> 4;
    f4v acc[4][4];
#pragma unroll
    for (int i = 0; i < 4; i++)
#pragma unroll
        for (int j = 0; j < 4; j++) acc[i][j] = f4v{0.f, 0.f, 0.f, 0.f};
    int srow = tid >> 1, ssub = (tid & 1) * 16;
    for (int k0 = 0; k0 < Kp; k0 += 32) {
        __syncthreads();
        {
            const uint4* g = (const uint4*)&A[(size_t)(m0 + srow) * Kp + k0 + ssub];
            uint4* l = (uint4*)&As[srow * 32 + ssub];
            l[0] = g[0]; l[1] = g[1];
        }
        {
            const uint4* g = (const uint4*)&W[(size_t)srow * Kp + k0 + ssub];
            uint4* l = (uint4*)&Bs[srow * 32 + ssub];
            l[0] = g[0]; l[1] = g[1];
        }
        __syncthreads();
        s8v af[4], bfr[4];
#pragma unroll
        for (int mi = 0; mi < 4; mi++) af[mi] = *(const s8v*)&As[(wm + mi * 16 + lm) * 32 + lq * 8];
#pragma unroll
        for (int ni = 0; ni < 4; ni++) bfr[ni] = *(const s8v*)&Bs[(wn + ni * 16 + lm) * 32 + lq * 8];
#pragma unroll
        for (int mi = 0; mi < 4; mi++)
#pragma unroll
            for (int ni = 0; ni < 4; ni++)
                acc[mi][ni] = __builtin_amdgcn_mfma_f32_16x16x32_bf16(af[mi], bfr[ni], acc[mi][ni], 0, 0, 0);
    }
#pragma unroll
    for (int mi = 0; mi < 4; mi++)
#pragma unroll
        for (int ni = 0; ni < 4; ni++)
#pragma unroll
            for (int r = 0; r < 4; r++) {
                int m = m0 + wm + mi * 16 + lq * 4 + r;
                int n = wn + ni * 16 + lm;
                int row = rowOff + (m >> 8), x = m & 255;
                float v = acc[mi][ni][r] + bias[n];
                out[((size_t)row * 258 + 1 + x) * 128 + n] = __float2bfloat16(gelu_tanh(v));
            }
}

// ================= MFMA tap-GEMM conv (#2/#3): 3 kx-taps per barrier =================
// Block = one output x-row (od,oh). A staged pre-shifted: As[3][BM][32]; B: Bs[3][128][32].
// Grid: (OC/128, OD*OH). Per (kz,ky,ic-chunk): 1 barrier pair, 3*16 (BM=128) MFMAs.
template <int BM, int KD>
__global__ __launch_bounds__(256) void conv_mfma2(
    const bf16* __restrict__ in, const bf16* __restrict__ wr, const float* __restrict__ bias,
    bf16* __restrict__ out, int ID, int IH, int IWp, int IC,
    int OH, int OC, int OWS, int outPad)
{
    constexpr int NI = (BM == 128) ? 4 : 2;
    __shared__ __align__(16) bf16 As[3 * BM * 32];
    __shared__ __align__(16) bf16 Bs[3 * 128 * 32];
    int tid = threadIdx.x;
    int n0 = blockIdx.x * 128;
    int rowid = blockIdx.y;
    int od = rowid / OH, oh = rowid % OH;
    int wave = tid >> 6, lane = tid & 63;
    int wm = (BM == 128) ? (wave >> 1) * 64 : 0;
    int wn = (BM == 128) ? (wave & 1) * 64 : wave * 32;
    int lm = lane & 15, lq = lane >> 4;
    f4v acc[4][NI];
#pragma unroll
    for (int i = 0; i < 4; i++)
#pragma unroll
        for (int j = 0; j < NI; j++) acc[i][j] = f4v{0.f, 0.f, 0.f, 0.f};

    for (int kz = 0; kz < KD; kz++) {
        int iz = (KD == 3) ? (2 * od + kz - 1) : 0;
        if ((unsigned)iz >= (unsigned)ID) continue;
        for (int ky = 0; ky < 3; ky++) {
            int iy = 2 * oh + ky - 1;
            if ((unsigned)iy >= (unsigned)IH) continue;
            const bf16* inrow = in + ((size_t)iz * IH + iy) * IWp * IC;
            const bf16* wbase = wr + (size_t)((kz * 3 + ky) * 3) * OC * IC;
            for (int kb = 0; kb < IC; kb += 32) {
                __syncthreads();
                for (int i = tid; i < 3 * BM * 4; i += 256) {
                    int kx = i / (BM * 4);
                    int r = i - kx * (BM * 4);
                    int m = r >> 2, sub = r & 3;
                    ((uint4*)As)[i] = ((const uint4*)&inrow[(size_t)(2 * m + kx) * IC + kb])[sub];
                }
                for (int i = tid; i < 1536; i += 256) {
                    int t3 = i >> 9;
                    int r = i & 511;
                    int n = r >> 2, sub = r & 3;
                    ((uint4*)Bs)[i] = ((const uint4*)&wbase[((size_t)t3 * OC + n0 + n) * IC + kb])[sub];
                }
                __syncthreads();
#pragma unroll
                for (int kx = 0; kx < 3; kx++) {
                    s8v af[4], bfr[NI];
#pragma unroll
                    for (int mi = 0; mi < 4; mi++)
                        af[mi] = *(const s8v*)&As[(kx * BM + wm + mi * 16 + lm) * 32 + lq * 8];
#pragma unroll
                    for (int ni = 0; ni < NI; ni++)
                        bfr[ni] = *(const s8v*)&Bs[(kx * 128 + wn + ni * 16 + lm) * 32 + lq * 8];
#pragma unroll
                    for (int mi = 0; mi < 4; mi++)
#pragma unroll
                        for (int ni = 0; ni < NI; ni++)
                            acc[mi][ni] = __builtin_amdgcn_mfma_f32_16x16x32_bf16(af[mi], bfr[ni], acc[mi][ni], 0, 0, 0);
                }
            }
        }
    }
    size_t orowbase = ((size_t)rowid * OWS + outPad) * OC;
#pragma unroll
    for (int mi = 0; mi < 4; mi++)
#pragma unroll
        for (int ni = 0; ni < NI; ni++)
#pragma unroll
            for (int r = 0; r < 4; r++) {
                int m = wm + mi * 16 + lq * 4 + r;
                int n = n0 + wn + ni * 16 + lm;
                float v = acc[mi][ni][r] + bias[n];
                out[orowbase + (size_t)m * OC + n] = __float2bfloat16(gelu_tanh(v));
            }
}

// ================= MFMA GEMM: C[M,N] = A[M,K] * Bt[N,K]^T + bias (+res) =================
template <typename OutT, int RES>
__global__ __launch_bounds__(256) void gemm_bt(
    const bf16* __restrict__ A, const bf16* __restrict__ Bt, const float* __restrict__ bias,
    OutT* __restrict__ C, const float* __restrict__ res, int M, int N, int K)
{
    __shared__ __align__(16) bf16 As[128 * 32];
    __shared__ __align__(16) bf16 Bs[128 * 32];
    int tid = threadIdx.x;
    int n0 = blockIdx.x * 128, m0 = blockIdx.y * 128;
    int wave = tid >> 6, lane = tid & 63;
    int wm = (wave >> 1) * 64, wn = (wave & 1) * 64;
    int lm = lane & 15, lq = lane >> 4;
    f4v acc[4][4];
#pragma unroll
    for (int i = 0; i < 4; i++)
#pragma unroll
        for (int j = 0; j < 4; j++) acc[i][j] = f4v{0.f, 0.f, 0.f, 0.f};
    int srow = tid >> 1, ssub = (tid & 1) * 16;
    for (int k0 = 0; k0 < K; k0 += 32) {
        __syncthreads();
        {
            const uint4* g = (const uint4*)&A[(size_t)(m0 + srow) * K + k0 + ssub];
            uint4* l = (uint4*)&As[srow * 32 + ssub];
            l[0] = g[0]; l[1] = g[1];
        }
        {
            const uint4* g = (const uint4*)&Bt[(size_t)(n0 + srow) * K + k0 + ssub];
            uint4* l = (uint4*)&Bs[srow * 32 + ssub];
            l[0] = g[0]; l[1] = g[1];
        }
        __syncthreads();
        s8v af[4], bfr[4];
#pragma unroll
        for (int mi = 0; mi < 4; mi++) af[mi] = *(const s8v*)&As[(wm + mi * 16 + lm) * 32 + lq * 8];
#pragma unroll
        for (int ni = 0; ni < 4; ni++) bfr[ni] = *(const s8v*)&Bs[(wn + ni * 16 + lm) * 32 + lq * 8];
#pragma unroll
        for (int mi = 0; mi < 4; mi++)
#pragma unroll
            for (int ni = 0; ni < 4; ni++)
                acc[mi][ni] = __builtin_amdgcn_mfma_f32_16x16x32_bf16(af[mi], bfr[ni], acc[mi][ni], 0, 0, 0);
    }
#pragma unroll
    for (int mi = 0; mi < 4; mi++)
#pragma unroll
        for (int ni = 0; ni < 4; ni++)
#pragma unroll
            for (int r = 0; r < 4; r++) {
                int m = m0 + wm + mi * 16 + lq * 4 + r;
                int n = n0 + wn + ni * 16 + lm;
                float v = acc[mi][ni][r] + bias[n];
                if (RES) v += res[(size_t)m * N + n];
                stf(&C[(size_t)m * N + n], v);
            }
}

// ---------------- LayerNorm: lat fp32 [P,512] -> y bf16 [P,512]; one wave per token ----------------
__global__ __launch_bounds__(256) void ln_k(
    const float* __restrict__ lat, const float* __restrict__ g, const float* __restrict__ b,
    bf16* __restrict__ y)
{
    int tok = blockIdx.x * 4 + (threadIdx.x >> 6);
    int lane = threadIdx.x & 63;
    const float4* row = (const float4*)&lat[(size_t)tok * 512 + lane * 8];
    float4 a = row[0], c = row[1];
    float s = a.x + a.y + a.z + a.w + c.x + c.y + c.z + c.w;
    float ss = a.x * a.x + a.y * a.y + a.z * a.z + a.w * a.w
             + c.x * c.x + c.y * c.y + c.z * c.z + c.w * c.w;
#pragma unroll
    for (int off = 32; off; off >>= 1) {
        s += __shfl_xor(s, off);
        ss += __shfl_xor(ss, off);
    }
    float mu = s * (1.f / 512.f);
    float var = ss * (1.f / 512.f) - mu * mu;
    float rstd = rsqrtf(var + 1e-5f);
    const float4* gp = (const float4*)&g[lane * 8];
    const float4* bp = (const float4*)&b[lane * 8];
    float4 g0 = gp[0], g1 = gp[1], b0 = bp[0], b1 = bp[1];
    union { uint4 u; unsigned short h[8]; } pk;
    pk.h[0] = bfbits((a.x - mu) * rstd * g0.x + b0.x);
    pk.h[1] = bfbits((a.y - mu) * rstd * g0.y + b0.y);
    pk.h[2] = bfbits((a.z - mu) * rstd * g0.z + b0.z);
    pk.h[3] = bfbits((a.w - mu) * rstd * g0.w + b0.w);
    pk.h[4] = bfbits((c.x - mu) * rstd * g1.x + b1.x);
    pk.h[5] = bfbits((c.y - mu) * rstd * g1.y + b1.y);
    pk.h[6] = bfbits((c.z - mu) * rstd * g1.z + b1.z);
    pk.h[7] = bfbits((c.w - mu) * rstd * g1.w + b1.w);
    *(uint4*)&y[(size_t)tok * 512 + lane * 8] = pk.u;
}

// ---------------- neighborhood attention: one wave per (pos, head); qkv bf16 [P,1536] ----------------
__global__ __launch_bounds__(256) void natt_k(
    const bf16* __restrict__ qkv, bf16* __restrict__ o)
{
    int unit = blockIdx.x * 4 + (threadIdx.x >> 6);
    int lane = threadIdx.x & 63;
    int head = unit & 7;
    int pos = unit >> 3;
    int w = pos & 63, h = (pos >> 6) & 31, d = pos >> 11;
    float q = ldf(&qkv[(size_t)pos * 1536 + head * 64 + lane]) * 0.125f;
    float m = -1e30f, l = 0.f, oa = 0.f;
    for (int dz = -2; dz <= 2; dz++) {
        int zz = d + dz;
        if ((unsigned)zz >= 4u) continue;
        for (int dy = -3; dy <= 3; dy++) {
            int yy = h + dy;
            if ((unsigned)yy >= 32u) continue;
            int rb = (zz * 32 + yy) * 64;
            for (int dx = -3; dx <= 3; dx++) {
                int xx = w + dx;
                if ((unsigned)xx >= 64u) continue;
                size_t nb = (size_t)(rb + xx) * 1536 + 512 + head * 64 + lane;
                float t = q * ldf(&qkv[nb]);
#pragma unroll
                for (int off = 32; off; off >>= 1) t += __shfl_xor(t, off);
                float mn = fmaxf(m, t);
                float al = __expf(m - mn);
                float p = __expf(t - mn);
                l = l * al + p;
                oa = fmaf(p, ldf(&qkv[nb + 512]), oa * al);
                m = mn;
            }
        }
    }
    o[(size_t)pos * 512 + head * 64 + lane] = __float2bfloat16(oa / l);
}

// ---------------- final transpose: lat [P,512] fp32 -> out planar [512,P] ----------------
__global__ __launch_bounds__(256) void tout_k(const float* __restrict__ lat, float* __restrict__ out)
{
    __shared__ float t[64][65];
    int p0 = blockIdx.x * 64, c0 = blockIdx.y * 64;
    for (int i = threadIdx.x; i < 4096; i += 256) {
        int r = i >> 6, cc = i & 63;
        t[r][cc] = lat[(size_t)(p0 + r) * 512 + c0 + cc];
    }
    __syncthreads();
    for (int i = threadIdx.x; i < 4096; i += 256) {
        int cc = i >> 6, r = i & 63;
        out[(size_t)(c0 + cc) * 8192 + p0 + r] = t[r][cc];
    }
}

extern "C" void kernel_launch(void* const* d_in, const int* in_sizes, int n_in,
                              void* d_out, int out_size, void* d_ws, size_t ws_size,
                              hipStream_t stream)
{
    const float* x2d = (const float*)d_in[0];
    const float* x3d = (const float*)d_in[1];
    const float* sw0 = (const float*)d_in[2];
    const float* sb0 = (const float*)d_in[3];
    const float* sw1 = (const float*)d_in[4];
    const float* sb1 = (const float*)d_in[5];
    const float* sw2 = (const float*)d_in[6];
    const float* sb2 = (const float*)d_in[7];
    const float* pw0 = (const float*)d_in[8];
    const float* pb0 = (const float*)d_in[9];
    const float* pw1 = (const float*)d_in[10];
    const float* pb1 = (const float*)d_in[11];
    const float* pw2 = (const float*)d_in[12];
    const float* pb2 = (const float*)d_in[13];
    const float* latw = (const float*)d_in[14];
    const float* latb = (const float*)d_in[15];
    const float* lng = (const float*)d_in[16];
    const float* lnb = (const float*)d_in[17];
    const float* qkvw = (const float*)d_in[18];
    const float* qkvb = (const float*)d_in[19];
    const float* projw = (const float*)d_in[20];
    const float* projb = (const float*)d_in[21];
    float* outp = (float*)d_out;

    char* ws = (char*)d_ws;
    // layout (bytes):
    bf16* p0pad = (bf16*)(ws + 0);              // [12][128][258][128] = 101,449,728
    bf16* wr3d2 = (bf16*)(ws + 101449728ull);   // 1,769,472
    bf16* wr3d3 = (bf16*)(ws + 103219200ull);   // 7,077,888
    bf16* wr2d2 = (bf16*)(ws + 110297088ull);   //   589,824
    bf16* wr2d3 = (bf16*)(ws + 110886912ull);   // 2,359,296
    bf16* qkvt  = (bf16*)(ws + 113246208ull);   // 4,718,592
    bf16* projt = (bf16*)(ws + 117964800ull);   // 1,572,864
    bf16* latbf = (bf16*)(ws + 119537664ull);   //   524,288
    bf16* w13d  = (bf16*)(ws + 120061952ull);   //    40,960
    bf16* w12d  = (bf16*)(ws + 120102912ull);   //    24,576
    bf16* p1pad = (bf16*)(ws + 120127488ull);   // [6][64][130][256] = 25,559,040
    bf16* s0pad = (bf16*)(ws + 145686528ull);   // [128][258][128]   =  8,454,144
    bf16* s1pad = (bf16*)(ws + 154140672ull);   // [64][130][256]    =  4,259,840
    bf16* featsT= (bf16*)(ws + 158400512ull);   // [8192][512]       =  8,388,608
    float* lat  = (float*)(ws + 166789120ull);  // [8192][512] fp32  = 16,777,216 -> 183,566,336
    // transient aliases:
    bf16* A3 = (bf16*)(ws + 120127488ull);      // im2col 3d half: 196608*160*2 = 62,914,560 (over p1..lat)
    bf16* A2 = (bf16*)(ws + 158400512ull);      // im2col 2d: 32768*96*2 = 6,291,456 (over featsT)
    // attention-phase aliases in dead p0pad region:
    bf16* ybf    = (bf16*)(ws + 0);
    bf16* qkvbuf = (bf16*)(ws + 8388608ull);
    bf16* attno  = (bf16*)(ws + 33554432ull);

    // 1) weight prep
    wprep_k<<<3456, 256, 0, stream>>>(pw1, wr3d2, 256, 128, 27);
    wprep_k<<<13824, 256, 0, stream>>>(pw2, wr3d3, 512, 256, 27);
    wprep_k<<<1152, 256, 0, stream>>>(sw1, wr2d2, 256, 128, 9);
    wprep_k<<<4608, 256, 0, stream>>>(sw2, wr2d3, 512, 256, 9);
    for (int r = 0; r < 3; r++) {
        tprep_k<<<3072, 256, 0, stream>>>(qkvw + (size_t)r * 786432, qkvt + (size_t)r * 786432, 512, 1536);
        tprep_k<<<1024, 256, 0, stream>>>(projw + (size_t)r * 262144, projt + (size_t)r * 262144, 512, 512);
    }
    cast_k<<<1024, 256, 0, stream>>>(latw, latbf, 262144);
    w1prep_k<<<80, 256, 0, stream>>>(pw0, w13d, 128, 5, 27, 160);
    w1prep_k<<<48, 256, 0, stream>>>(sw0, w12d, 128, 8, 9, 96);

    // 2) zero p0pad (halo)
    fill0_k<<<24768, 256, 0, stream>>>((uint4*)p0pad, 6340608);

    // 3) conv3d#1 via im2col + MFMA GEMM, two od-halves
    im2col3d_k<<<15360, 256, 0, stream>>>(x3d, A3, 0);
    conv1_gemm<<<1536, 256, 0, stream>>>(A3, w13d, pb0, p0pad, 196608, 160, 0);
    im2col3d_k<<<15360, 256, 0, stream>>>(x3d, A3, 6);
    conv1_gemm<<<1536, 256, 0, stream>>>(A3, w13d, pb0, p0pad, 196608, 160, 768);

    // 4) zero p1pad+s0pad+s1pad (halos); then conv2d#1
    fill0_k<<<9344, 256, 0, stream>>>((uint4*)p1pad, 2392064);
    im2col2d_k<<<1536, 256, 0, stream>>>(x2d, A2);
    conv1_gemm<<<256, 256, 0, stream>>>(A2, w12d, sb0, s0pad, 32768, 96, 0);

    // 5) conv chains (#2/#3)
    conv_mfma2<128, 1><<<dim3(2, 64), 256, 0, stream>>>(s0pad, wr2d2, sb1, s1pad, 1, 128, 258, 128, 64, 256, 130, 1);
    conv_mfma2<64, 1><<<dim3(4, 32), 256, 0, stream>>>(s1pad, wr2d3, sb2, featsT + (size_t)6144 * 512, 1, 64, 130, 256, 32, 512, 64, 0);
    conv_mfma2<128, 3><<<dim3(2, 384), 256, 0, stream>>>(p0pad, wr3d2, pb1, p1pad, 12, 128, 258, 128, 64, 256, 130, 1);
    conv_mfma2<64, 3><<<dim3(4, 96), 256, 0, stream>>>(p1pad, wr3d3, pb2, featsT, 6, 64, 130, 256, 32, 512, 64, 0);

    // 6) lateral 1x1 conv
    gemm_bt<float, 0><<<dim3(4, 64), 256, 0, stream>>>(featsT, latbf, latb, lat, nullptr, 8192, 512, 512);

    // 7) 3 attention rounds
    for (int r = 0; r < 3; r++) {
        ln_k<<<2048, 256, 0, stream>>>(lat, lng + r * 512, lnb + r * 512, ybf);
        gemm_bt<bf16, 0><<<dim3(12, 64), 256, 0, stream>>>(ybf, qkvt + (size_t)r * 786432, qkvb + r * 1536,
                                                           qkvbuf, nullptr, 8192, 1536, 512);
        natt_k<<<16384, 256, 0, stream>>>(qkvbuf, attno);
        gemm_bt<float, 1><<<dim3(4, 64), 256, 0, stream>>>(attno, projt + (size_t)r * 262144, projb + r * 512,
                                                           lat, lat, 8192, 512, 512);
    }

    // 8) transpose to planar output [512][4][32][64]
    tout_k<<<dim3(128, 8), 256, 0, stream>>>(lat, outp);
}

// Round 6
// 1542.847 us; speedup vs baseline: 32.1608x; 2.1234x over previous
//
#include <hip/hip_runtime.h>
#include <hip/hip_bf16.h>
#include <math.h>

typedef __hip_bfloat16 bf16;
typedef __attribute__((ext_vector_type(8))) short s8v;
typedef __attribute__((ext_vector_type(4))) float f4v;

__device__ __forceinline__ float ldf(const float* p) { return *p; }
__device__ __forceinline__ float ldf(const bf16* p) { return __bfloat162float(*p); }
__device__ __forceinline__ void stf(float* p, float v) { *p = v; }
__device__ __forceinline__ void stf(bf16* p, float v) { *p = __float2bfloat16(v); }

__device__ __forceinline__ float gelu_tanh(float x) {
    float x3 = x * x * x;
    return 0.5f * x * (1.f + tanhf(0.7978845608028654f * (x + 0.044715f * x3)));
}
__device__ __forceinline__ unsigned short bfbits(float x) {
    bf16 t = __float2bfloat16(x);
    return *(unsigned short*)&t;
}

// ---------------- zero fill (16B granules) ----------------
__global__ __launch_bounds__(256) void fill0_k(uint4* __restrict__ p, int n16)
{
    int i = blockIdx.x * 256 + threadIdx.x;
    if (i < n16) p[i] = uint4{0u, 0u, 0u, 0u};
}

// ---------------- weight reorder: fp32 [OC][IC][T] -> bf16 [T][OC][IC] ----------------
__global__ __launch_bounds__(256) void wprep_k(const float* __restrict__ w, bf16* __restrict__ wr,
                                               int OC, int IC, int T)
{
    int i = blockIdx.x * 256 + threadIdx.x;
    if (i >= OC * IC * T) return;
    int t = i % T; int rem = i / T; int ic = rem % IC; int oc = rem / IC;
    wr[((size_t)t * OC + oc) * IC + ic] = __float2bfloat16(w[i]);
}

// ---------------- conv#1 weight prep: fp32 [OC][nic][ntap] -> bf16 [OC][Kp], k=tap*nic+ic ----------------
__global__ __launch_bounds__(256) void w1prep_k(const float* __restrict__ w, bf16* __restrict__ o,
                                                int OC, int nic, int ntap, int Kp)
{
    int i = blockIdx.x * 256 + threadIdx.x;
    if (i >= OC * Kp) return;
    int oc = i / Kp, k = i - oc * Kp;
    float v = 0.f;
    if (k < nic * ntap) {
        int tap = k / nic, ic = k - tap * nic;
        v = w[((size_t)oc * nic + ic) * ntap + tap];
    }
    o[i] = __float2bfloat16(v);
}

// ---------------- transpose cast: fp32 [K][N] -> bf16 [N][K] ----------------
__global__ __launch_bounds__(256) void tprep_k(const float* __restrict__ w, bf16* __restrict__ wt,
                                               int K, int N)
{
    int i = blockIdx.x * 256 + threadIdx.x;
    if (i >= K * N) return;
    int n = i % N, k = i / N;
    wt[(size_t)n * K + k] = __float2bfloat16(w[i]);
}

// ---------------- plain cast fp32 -> bf16 ----------------
__global__ __launch_bounds__(256) void cast_k(const float* __restrict__ w, bf16* __restrict__ o, int n)
{
    int i = blockIdx.x * 256 + threadIdx.x;
    if (i < n) o[i] = __float2bfloat16(w[i]);
}

// ---------------- im2col for conv3d#1: x3d fp32 [5][24][256][512] -> A bf16 [196608][160] ----------------
__global__ __launch_bounds__(256) void im2col3d_k(const float* __restrict__ x, bf16* __restrict__ A, int od0)
{
    int gid = blockIdx.x * 256 + threadIdx.x;  // 196608*20
    int m = gid / 20, kg = gid - 20 * (gid / 20);
    int ow = m & 255, rowid = m >> 8;
    int oh = rowid & 127, od = od0 + (rowid >> 7);
    int iz0 = 2 * od - 1, iy0 = 2 * oh - 1, ix0 = 2 * ow - 1;
    union { uint4 u; unsigned short h[8]; } pk;
#pragma unroll
    for (int j = 0; j < 8; j++) {
        int k = kg * 8 + j;
        float v = 0.f;
        if (k < 135) {
            int tap = k / 5, ic = k - tap * 5;
            int kz = tap / 9, r = tap - kz * 9;
            int ky = r / 3, kx = r - ky * 3;
            int iz = iz0 + kz, iy = iy0 + ky, ix = ix0 + kx;
            if ((unsigned)iz < 24u && (unsigned)iy < 256u && (unsigned)ix < 512u)
                v = x[(((size_t)ic * 24 + iz) * 256 + iy) * 512 + ix];
        }
        pk.h[j] = bfbits(v);
    }
    *(uint4*)&A[(size_t)m * 160 + kg * 8] = pk.u;
}

// ---------------- im2col for conv2d#1: x2d fp32 [8][256][512] -> A bf16 [32768][96] ----------------
__global__ __launch_bounds__(256) void im2col2d_k(const float* __restrict__ x, bf16* __restrict__ A)
{
    int gid = blockIdx.x * 256 + threadIdx.x;  // 32768*12
    int m = gid / 12, kg = gid - 12 * (gid / 12);
    int ow = m & 255, oh = m >> 8;
    int iy0 = 2 * oh - 1, ix0 = 2 * ow - 1;
    union { uint4 u; unsigned short h[8]; } pk;
#pragma unroll
    for (int j = 0; j < 8; j++) {
        int k = kg * 8 + j;
        float v = 0.f;
        if (k < 72) {
            int tap = k >> 3, ic = k & 7;
            int ky = tap / 3, kx = tap - ky * 3;
            int iy = iy0 + ky, ix = ix0 + kx;
            if ((unsigned)iy < 256u && (unsigned)ix < 512u)
                v = x[((size_t)ic * 256 + iy) * 512 + ix];
        }
        pk.h[j] = bfbits(v);
    }
    *(uint4*)&A[(size_t)m * 96 + kg * 8] = pk.u;
}

// ---------------- conv#1 GEMM: C = A[M][Kp] x W[128][Kp]^T, +bias, GELU, padded NHWC store ----------------
__global__ __launch_bounds__(256) void conv1_gemm(
    const bf16* __restrict__ A, const bf16* __restrict__ W, const float* __restrict__ bias,
    bf16* __restrict__ out, int M, int Kp, int rowOff)
{
    __shared__ __align__(16) bf16 As[128 * 32];
    __shared__ __align__(16) bf16 Bs[128 * 32];
    int tid = threadIdx.x;
    int m0 = blockIdx.x * 128;
    int wave = tid >> 6, lane = tid & 63;
    int wm = (wave >> 1) * 64, wn = (wave & 1) * 64;
    int lm = lane & 15, lq = lane >> 4;
    f4v acc[4][4];
#pragma unroll
    for (int i = 0; i < 4; i++)
#pragma unroll
        for (int j = 0; j < 4; j++) acc[i][j] = f4v{0.f, 0.f, 0.f, 0.f};
    int srow = tid >> 1, ssub = (tid & 1) * 16;
    for (int k0 = 0; k0 < Kp; k0 += 32) {
        __syncthreads();
        {
            const uint4* g = (const uint4*)&A[(size_t)(m0 + srow) * Kp + k0 + ssub];
            uint4* l = (uint4*)&As[srow * 32 + ssub];
            l[0] = g[0]; l[1] = g[1];
        }
        {
            const uint4* g = (const uint4*)&W[(size_t)srow * Kp + k0 + ssub];
            uint4* l = (uint4*)&Bs[srow * 32 + ssub];
            l[0] = g[0]; l[1] = g[1];
        }
        __syncthreads();
        s8v af[4], bfr[4];
#pragma unroll
        for (int mi = 0; mi < 4; mi++) af[mi] = *(const s8v*)&As[(wm + mi * 16 + lm) * 32 + lq * 8];
#pragma unroll
        for (int ni = 0; ni < 4; ni++) bfr[ni] = *(const s8v*)&Bs[(wn + ni * 16 + lm) * 32 + lq * 8];
#pragma unroll
        for (int mi = 0; mi < 4; mi++)
#pragma unroll
            for (int ni = 0; ni < 4; ni++)
                acc[mi][ni] = __builtin_amdgcn_mfma_f32_16x16x32_bf16(af[mi], bfr[ni], acc[mi][ni], 0, 0, 0);
    }
#pragma unroll
    for (int mi = 0; mi < 4; mi++)
#pragma unroll
        for (int ni = 0; ni < 4; ni++)
#pragma unroll
            for (int r = 0; r < 4; r++) {
                int m = m0 + wm + mi * 16 + lq * 4 + r;
                int n = wn + ni * 16 + lm;
                int row = rowOff + (m >> 8), x = m & 255;
                float v = acc[mi][ni][r] + bias[n];
                out[((size_t)row * 258 + 1 + x) * 128 + n] = __float2bfloat16(gelu_tanh(v));
            }
}

// ================= MFMA tap-GEMM conv (#2/#3): 3 kx-taps per barrier =================
template <int BM, int KD>
__global__ __launch_bounds__(256) void conv_mfma2(
    const bf16* __restrict__ in, const bf16* __restrict__ wr, const float* __restrict__ bias,
    bf16* __restrict__ out, int ID, int IH, int IWp, int IC,
    int OH, int OC, int OWS, int outPad)
{
    constexpr int NI = (BM == 128) ? 4 : 2;
    __shared__ __align__(16) bf16 As[3 * BM * 32];
    __shared__ __align__(16) bf16 Bs[3 * 128 * 32];
    int tid = threadIdx.x;
    int n0 = blockIdx.x * 128;
    int rowid = blockIdx.y;
    int od = rowid / OH, oh = rowid % OH;
    int wave = tid >> 6, lane = tid & 63;
    int wm = (BM == 128) ? (wave >> 1) * 64 : 0;
    int wn = (BM == 128) ? (wave & 1) * 64 : wave * 32;
    int lm = lane & 15, lq = lane >> 4;
    f4v acc[4][NI];
#pragma unroll
    for (int i = 0; i < 4; i++)
#pragma unroll
        for (int j = 0; j < NI; j++) acc[i][j] = f4v{0.f, 0.f, 0.f, 0.f};

    for (int kz = 0; kz < KD; kz++) {
        int iz = (KD == 3) ? (2 * od + kz - 1) : 0;
        if ((unsigned)iz >= (unsigned)ID) continue;
        for (int ky = 0; ky < 3; ky++) {
            int iy = 2 * oh + ky - 1;
            if ((unsigned)iy >= (unsigned)IH) continue;
            const bf16* inrow = in + ((size_t)iz * IH + iy) * IWp * IC;
            const bf16* wbase = wr + (size_t)((kz * 3 + ky) * 3) * OC * IC;
            for (int kb = 0; kb < IC; kb += 32) {
                __syncthreads();
                for (int i = tid; i < 3 * BM * 4; i += 256) {
                    int kx = i / (BM * 4);
                    int r = i - kx * (BM * 4);
                    int m = r >> 2, sub = r & 3;
                    ((uint4*)As)[i] = ((const uint4*)&inrow[(size_t)(2 * m + kx) * IC + kb])[sub];
                }
                for (int i = tid; i < 1536; i += 256) {
                    int t3 = i >> 9;
                    int r = i & 511;
                    int n = r >> 2, sub = r & 3;
                    ((uint4*)Bs)[i] = ((const uint4*)&wbase[((size_t)t3 * OC + n0 + n) * IC + kb])[sub];
                }
                __syncthreads();
#pragma unroll
                for (int kx = 0; kx < 3; kx++) {
                    s8v af[4], bfr[NI];
#pragma unroll
                    for (int mi = 0; mi < 4; mi++)
                        af[mi] = *(const s8v*)&As[(kx * BM + wm + mi * 16 + lm) * 32 + lq * 8];
#pragma unroll
                    for (int ni = 0; ni < NI; ni++)
                        bfr[ni] = *(const s8v*)&Bs[(kx * 128 + wn + ni * 16 + lm) * 32 + lq * 8];
#pragma unroll
                    for (int mi = 0; mi < 4; mi++)
#pragma unroll
                        for (int ni = 0; ni < NI; ni++)
                            acc[mi][ni] = __builtin_amdgcn_mfma_f32_16x16x32_bf16(af[mi], bfr[ni], acc[mi][ni], 0, 0, 0);
                }
            }
        }
    }
    size_t orowbase = ((size_t)rowid * OWS + outPad) * OC;
#pragma unroll
    for (int mi = 0; mi < 4; mi++)
#pragma unroll
        for (int ni = 0; ni < NI; ni++)
#pragma unroll
            for (int r = 0; r < 4; r++) {
                int m = wm + mi * 16 + lq * 4 + r;
                int n = n0 + wn + ni * 16 + lm;
                float v = acc[mi][ni][r] + bias[n];
                out[orowbase + (size_t)m * OC + n] = __float2bfloat16(gelu_tanh(v));
            }
}

// ================= MFMA GEMM: C[M,N] = A[M,K] * Bt[N,K]^T + bias (+res) (+vT side-write) ==========
template <typename OutT, int RES, int VT>
__global__ __launch_bounds__(256) void gemm_bt(
    const bf16* __restrict__ A, const bf16* __restrict__ Bt, const float* __restrict__ bias,
    OutT* __restrict__ C, const float* __restrict__ res, bf16* __restrict__ vt,
    int M, int N, int K)
{
    __shared__ __align__(16) bf16 As[128 * 32];
    __shared__ __align__(16) bf16 Bs[128 * 32];
    int tid = threadIdx.x;
    int n0 = blockIdx.x * 128, m0 = blockIdx.y * 128;
    int wave = tid >> 6, lane = tid & 63;
    int wm = (wave >> 1) * 64, wn = (wave & 1) * 64;
    int lm = lane & 15, lq = lane >> 4;
    f4v acc[4][4];
#pragma unroll
    for (int i = 0; i < 4; i++)
#pragma unroll
        for (int j = 0; j < 4; j++) acc[i][j] = f4v{0.f, 0.f, 0.f, 0.f};
    int srow = tid >> 1, ssub = (tid & 1) * 16;
    for (int k0 = 0; k0 < K; k0 += 32) {
        __syncthreads();
        {
            const uint4* g = (const uint4*)&A[(size_t)(m0 + srow) * K + k0 + ssub];
            uint4* l = (uint4*)&As[srow * 32 + ssub];
            l[0] = g[0]; l[1] = g[1];
        }
        {
            const uint4* g = (const uint4*)&Bt[(size_t)(n0 + srow) * K + k0 + ssub];
            uint4* l = (uint4*)&Bs[srow * 32 + ssub];
            l[0] = g[0]; l[1] = g[1];
        }
        __syncthreads();
        s8v af[4], bfr[4];
#pragma unroll
        for (int mi = 0; mi < 4; mi++) af[mi] = *(const s8v*)&As[(wm + mi * 16 + lm) * 32 + lq * 8];
#pragma unroll
        for (int ni = 0; ni < 4; ni++) bfr[ni] = *(const s8v*)&Bs[(wn + ni * 16 + lm) * 32 + lq * 8];
#pragma unroll
        for (int mi = 0; mi < 4; mi++)
#pragma unroll
            for (int ni = 0; ni < 4; ni++)
                acc[mi][ni] = __builtin_amdgcn_mfma_f32_16x16x32_bf16(af[mi], bfr[ni], acc[mi][ni], 0, 0, 0);
    }
#pragma unroll
    for (int mi = 0; mi < 4; mi++)
#pragma unroll
        for (int ni = 0; ni < 4; ni++) {
            int n = n0 + wn + ni * 16 + lm;
            int mbase = m0 + wm + mi * 16 + lq * 4;
            float b = bias[n];
            if (VT && n >= 1024) {
                ushort4 pk;
                pk.x = bfbits(acc[mi][ni][0] + b);
                pk.y = bfbits(acc[mi][ni][1] + b);
                pk.z = bfbits(acc[mi][ni][2] + b);
                pk.w = bfbits(acc[mi][ni][3] + b);
                *(ushort4*)&vt[(size_t)(n - 1024) * 8192 + mbase] = pk;
            }
#pragma unroll
            for (int r = 0; r < 4; r++) {
                int m = mbase + r;
                float v = acc[mi][ni][r] + b;
                if (RES) v += res[(size_t)m * N + n];
                stf(&C[(size_t)m * N + n], v);
            }
        }
}

// ---------------- LayerNorm: lat fp32 [P,512] -> y bf16 [P,512]; one wave per token ----------------
__global__ __launch_bounds__(256) void ln_k(
    const float* __restrict__ lat, const float* __restrict__ g, const float* __restrict__ b,
    bf16* __restrict__ y)
{
    int tok = blockIdx.x * 4 + (threadIdx.x >> 6);
    int lane = threadIdx.x & 63;
    const float4* row = (const float4*)&lat[(size_t)tok * 512 + lane * 8];
    float4 a = row[0], c = row[1];
    float s = a.x + a.y + a.z + a.w + c.x + c.y + c.z + c.w;
    float ss = a.x * a.x + a.y * a.y + a.z * a.z + a.w * a.w
             + c.x * c.x + c.y * c.y + c.z * c.z + c.w * c.w;
#pragma unroll
    for (int off = 32; off; off >>= 1) {
        s += __shfl_xor(s, off);
        ss += __shfl_xor(ss, off);
    }
    float mu = s * (1.f / 512.f);
    float var = ss * (1.f / 512.f) - mu * mu;
    float rstd = rsqrtf(var + 1e-5f);
    const float4* gp = (const float4*)&g[lane * 8];
    const float4* bp = (const float4*)&b[lane * 8];
    float4 g0 = gp[0], g1 = gp[1], b0 = bp[0], b1 = bp[1];
    union { uint4 u; unsigned short h[8]; } pk;
    pk.h[0] = bfbits((a.x - mu) * rstd * g0.x + b0.x);
    pk.h[1] = bfbits((a.y - mu) * rstd * g0.y + b0.y);
    pk.h[2] = bfbits((a.z - mu) * rstd * g0.z + b0.z);
    pk.h[3] = bfbits((a.w - mu) * rstd * g0.w + b0.w);
    pk.h[4] = bfbits((c.x - mu) * rstd * g1.x + b1.x);
    pk.h[5] = bfbits((c.y - mu) * rstd * g1.y + b1.y);
    pk.h[6] = bfbits((c.z - mu) * rstd * g1.z + b1.z);
    pk.h[7] = bfbits((c.w - mu) * rstd * g1.w + b1.w);
    *(uint4*)&y[(size_t)tok * 512 + lane * 8] = pk.u;
}

// ================= MFMA flash-style neighborhood attention =================
// grid (128 rows, 8 heads); block 256 = 4 waves; wave handles (dz,dy) idx = wave + 4t.
// Per valid offset: S[64w][64x'] = Q.K^T (MFMA), band-mask, online softmax, P.V (MFMA).
__global__ __launch_bounds__(256) void natt_mfma(
    const bf16* __restrict__ qkv, const bf16* __restrict__ vT, bf16* __restrict__ o)
{
    __shared__ __align__(16) char smem[53248];
    bf16* qs = (bf16*)smem;                    // [64][80] bf16 (prologue only)
    float* obuf = (float*)smem;                // [64][65] fp32 (epilogue, aliases qs/pbuf)
    float* mlb = (float*)(smem + 51200);       // [4 waves][2][64]
    int tid = threadIdx.x;
    int rowid = blockIdx.x;                    // d*32 + h
    int head = blockIdx.y;
    int d = rowid >> 5, h = rowid & 31;
    int rowbase = rowid * 64;
    int hoff = head * 64;
    int wave = tid >> 6, lane = tid & 63;
    int lm = lane & 15, lq = lane >> 4;
    bf16* pb = (bf16*)(smem + 10240 + wave * 10240);  // per-wave P [64][80]

    // stage Q tile [64 tokens][64 dims]
    for (int i = tid; i < 512; i += 256) {
        int row = i >> 3, sub = i & 7;
        *(uint4*)&qs[row * 80 + sub * 8] =
            *(const uint4*)&qkv[(size_t)(rowbase + row) * 1536 + hoff + sub * 8];
    }
    __syncthreads();
    s8v qf[4][2];
#pragma unroll
    for (int mi = 0; mi < 4; mi++)
#pragma unroll
        for (int c = 0; c < 2; c++)
            qf[mi][c] = *(const s8v*)&qs[(mi * 16 + lm) * 80 + c * 32 + lq * 8];

    f4v Oa[4][4];
#pragma unroll
    for (int i = 0; i < 4; i++)
#pragma unroll
        for (int j = 0; j < 4; j++) Oa[i][j] = f4v{0.f, 0.f, 0.f, 0.f};
    float mr[4][4], lr[4][4];
#pragma unroll
    for (int i = 0; i < 4; i++)
#pragma unroll
        for (int j = 0; j < 4; j++) { mr[i][j] = -1e30f; lr[i][j] = 0.f; }

    for (int idx = wave; idx < 35; idx += 4) {
        int dz = idx / 7 - 2, dy = idx % 7 - 3;
        int zz = d + dz, yy = h + dy;
        if ((unsigned)zz >= 4u || (unsigned)yy >= 32u) continue;
        int kbase = (zz * 32 + yy) * 64;
        // S = Q K^T
        f4v s[4][4];
#pragma unroll
        for (int i = 0; i < 4; i++)
#pragma unroll
            for (int j = 0; j < 4; j++) s[i][j] = f4v{0.f, 0.f, 0.f, 0.f};
        {
            s8v kf[4][2];
#pragma unroll
            for (int ni = 0; ni < 4; ni++)
#pragma unroll
                for (int c = 0; c < 2; c++)
                    kf[ni][c] = *(const s8v*)&qkv[(size_t)(kbase + ni * 16 + lm) * 1536 + 512 + hoff + c * 32 + lq * 8];
#pragma unroll
            for (int c = 0; c < 2; c++)
#pragma unroll
                for (int mi = 0; mi < 4; mi++)
#pragma unroll
                    for (int ni = 0; ni < 4; ni++)
                        s[mi][ni] = __builtin_amdgcn_mfma_f32_16x16x32_bf16(qf[mi][c], kf[ni][c], s[mi][ni], 0, 0, 0);
        }
        // band-mask + online softmax; P -> LDS (bf16)
#pragma unroll
        for (int mi = 0; mi < 4; mi++) {
#pragma unroll
            for (int r = 0; r < 4; r++) {
                int w0 = mi * 16 + lq * 4 + r;
                float sv[4];
                float rm = -1e30f;
#pragma unroll
                for (int ni = 0; ni < 4; ni++) {
                    int xp = ni * 16 + lm;
                    float v = s[mi][ni][r] * 0.125f;
                    v = ((unsigned)(xp - w0 + 3) <= 6u) ? v : -1e30f;
                    sv[ni] = v;
                    rm = fmaxf(rm, v);
                }
#pragma unroll
                for (int off = 1; off <= 8; off <<= 1)
                    rm = fmaxf(rm, __shfl_xor(rm, off));
                float mn = fmaxf(mr[mi][r], rm);
                float al = __expf(mr[mi][r] - mn);
                mr[mi][r] = mn;
                float rs = 0.f;
#pragma unroll
                for (int ni = 0; ni < 4; ni++) {
                    float p = __expf(sv[ni] - mn);
                    rs += p;
                    pb[w0 * 80 + ni * 16 + lm] = __float2bfloat16(p);
                }
#pragma unroll
                for (int off = 1; off <= 8; off <<= 1)
                    rs += __shfl_xor(rs, off);
                lr[mi][r] = lr[mi][r] * al + rs;
#pragma unroll
                for (int nd = 0; nd < 4; nd++)
                    Oa[mi][nd][r] *= al;
            }
        }
        __asm__ __volatile__("s_waitcnt lgkmcnt(0)" ::: "memory");
        // O += P V
        {
            s8v pf[4][2], vf[4][2];
#pragma unroll
            for (int mi = 0; mi < 4; mi++)
#pragma unroll
                for (int c = 0; c < 2; c++)
                    pf[mi][c] = *(const s8v*)&pb[(mi * 16 + lm) * 80 + c * 32 + lq * 8];
#pragma unroll
            for (int nd = 0; nd < 4; nd++)
#pragma unroll
                for (int c = 0; c < 2; c++)
                    vf[nd][c] = *(const s8v*)&vT[(size_t)(hoff + nd * 16 + lm) * 8192 + kbase + c * 32 + lq * 8];
#pragma unroll
            for (int c = 0; c < 2; c++)
#pragma unroll
                for (int mi = 0; mi < 4; mi++)
#pragma unroll
                    for (int nd = 0; nd < 4; nd++)
                        Oa[mi][nd] = __builtin_amdgcn_mfma_f32_16x16x32_bf16(pf[mi][c], vf[nd][c], Oa[mi][nd], 0, 0, 0);
        }
    }
    // publish per-wave m,l
    if (lm == 0) {
#pragma unroll
        for (int mi = 0; mi < 4; mi++)
#pragma unroll
            for (int r = 0; r < 4; r++) {
                int row = mi * 16 + lq * 4 + r;
                mlb[wave * 128 + row] = mr[mi][r];
                mlb[wave * 128 + 64 + row] = lr[mi][r];
            }
    }
    __syncthreads();
    // sequential cross-wave combine into obuf
    for (int wv = 0; wv < 4; wv++) {
        if (wave == wv) {
#pragma unroll
            for (int mi = 0; mi < 4; mi++)
#pragma unroll
                for (int r = 0; r < 4; r++) {
                    int row = mi * 16 + lq * 4 + r;
                    float M = fmaxf(fmaxf(mlb[row], mlb[128 + row]),
                                    fmaxf(mlb[256 + row], mlb[384 + row]));
                    float sc = __expf(mr[mi][r] - M);
#pragma unroll
                    for (int nd = 0; nd < 4; nd++) {
                        int ci = row * 65 + nd * 16 + lm;
                        float add = Oa[mi][nd][r] * sc;
                        obuf[ci] = (wv == 0) ? add : (obuf[ci] + add);
                    }
                }
        }
        __syncthreads();
    }
    // final normalize + coalesced store
    {
        int row = tid >> 2, cb = (tid & 3) * 16;
        float m0 = mlb[row], m1 = mlb[128 + row], m2 = mlb[256 + row], m3 = mlb[384 + row];
        float M = fmaxf(fmaxf(m0, m1), fmaxf(m2, m3));
        float L = mlb[64 + row] * __expf(m0 - M) + mlb[192 + row] * __expf(m1 - M)
                + mlb[320 + row] * __expf(m2 - M) + mlb[448 + row] * __expf(m3 - M);
        float inv = 1.f / L;
        union { uint4 u[2]; unsigned short hs[16]; } pk;
#pragma unroll
        for (int j = 0; j < 16; j++)
            pk.hs[j] = bfbits(obuf[row * 65 + cb + j] * inv);
        *(uint4*)&o[(size_t)(rowbase + row) * 512 + hoff + cb] = pk.u[0];
        *(uint4*)&o[(size_t)(rowbase + row) * 512 + hoff + cb + 8] = pk.u[1];
    }
}

// ---------------- final transpose: lat [P,512] fp32 -> out planar [512,P] ----------------
__global__ __launch_bounds__(256) void tout_k(const float* __restrict__ lat, float* __restrict__ out)
{
    __shared__ float t[64][65];
    int p0 = blockIdx.x * 64, c0 = blockIdx.y * 64;
    for (int i = threadIdx.x; i < 4096; i += 256) {
        int r = i >> 6, cc = i & 63;
        t[r][cc] = lat[(size_t)(p0 + r) * 512 + c0 + cc];
    }
    __syncthreads();
    for (int i = threadIdx.x; i < 4096; i += 256) {
        int cc = i >> 6, r = i & 63;
        out[(size_t)(c0 + cc) * 8192 + p0 + r] = t[r][cc];
    }
}

extern "C" void kernel_launch(void* const* d_in, const int* in_sizes, int n_in,
                              void* d_out, int out_size, void* d_ws, size_t ws_size,
                              hipStream_t stream)
{
    const float* x2d = (const float*)d_in[0];
    const float* x3d = (const float*)d_in[1];
    const float* sw0 = (const float*)d_in[2];
    const float* sb0 = (const float*)d_in[3];
    const float* sw1 = (const float*)d_in[4];
    const float* sb1 = (const float*)d_in[5];
    const float* sw2 = (const float*)d_in[6];
    const float* sb2 = (const float*)d_in[7];
    const float* pw0 = (const float*)d_in[8];
    const float* pb0 = (const float*)d_in[9];
    const float* pw1 = (const float*)d_in[10];
    const float* pb1 = (const float*)d_in[11];
    const float* pw2 = (const float*)d_in[12];
    const float* pb2 = (const float*)d_in[13];
    const float* latw = (const float*)d_in[14];
    const float* latb = (const float*)d_in[15];
    const float* lng = (const float*)d_in[16];
    const float* lnb = (const float*)d_in[17];
    const float* qkvw = (const float*)d_in[18];
    const float* qkvb = (const float*)d_in[19];
    const float* projw = (const float*)d_in[20];
    const float* projb = (const float*)d_in[21];
    float* outp = (float*)d_out;

    char* ws = (char*)d_ws;
    bf16* p0pad = (bf16*)(ws + 0);              // [12][128][258][128] = 101,449,728
    bf16* wr3d2 = (bf16*)(ws + 101449728ull);
    bf16* wr3d3 = (bf16*)(ws + 103219200ull);
    bf16* wr2d2 = (bf16*)(ws + 110297088ull);
    bf16* wr2d3 = (bf16*)(ws + 110886912ull);
    bf16* qkvt  = (bf16*)(ws + 113246208ull);
    bf16* projt = (bf16*)(ws + 117964800ull);
    bf16* latbf = (bf16*)(ws + 119537664ull);
    bf16* w13d  = (bf16*)(ws + 120061952ull);
    bf16* w12d  = (bf16*)(ws + 120102912ull);
    bf16* p1pad = (bf16*)(ws + 120127488ull);   // [6][64][130][256]
    bf16* s0pad = (bf16*)(ws + 145686528ull);   // [128][258][128]
    bf16* s1pad = (bf16*)(ws + 154140672ull);   // [64][130][256]
    bf16* featsT= (bf16*)(ws + 158400512ull);   // [8192][512]
    float* lat  = (float*)(ws + 166789120ull);  // [8192][512] fp32 -> 183,566,336 total
    // transient aliases:
    bf16* A3 = (bf16*)(ws + 120127488ull);      // im2col 3d half (over p1..lat)
    bf16* A2 = (bf16*)(ws + 158400512ull);      // im2col 2d (over featsT)
    // attention-phase aliases in dead p0pad region:
    bf16* ybf    = (bf16*)(ws + 0);             //  8,388,608
    bf16* qkvbuf = (bf16*)(ws + 8388608ull);    // 25,165,824
    bf16* attno  = (bf16*)(ws + 33554432ull);   //  8,388,608
    bf16* vT     = (bf16*)(ws + 41943040ull);   //  8,388,608 [512][8192]

    // 1) weight prep
    wprep_k<<<3456, 256, 0, stream>>>(pw1, wr3d2, 256, 128, 27);
    wprep_k<<<13824, 256, 0, stream>>>(pw2, wr3d3, 512, 256, 27);
    wprep_k<<<1152, 256, 0, stream>>>(sw1, wr2d2, 256, 128, 9);
    wprep_k<<<4608, 256, 0, stream>>>(sw2, wr2d3, 512, 256, 9);
    for (int r = 0; r < 3; r++) {
        tprep_k<<<3072, 256, 0, stream>>>(qkvw + (size_t)r * 786432, qkvt + (size_t)r * 786432, 512, 1536);
        tprep_k<<<1024, 256, 0, stream>>>(projw + (size_t)r * 262144, projt + (size_t)r * 262144, 512, 512);
    }
    cast_k<<<1024, 256, 0, stream>>>(latw, latbf, 262144);
    w1prep_k<<<80, 256, 0, stream>>>(pw0, w13d, 128, 5, 27, 160);
    w1prep_k<<<48, 256, 0, stream>>>(sw0, w12d, 128, 8, 9, 96);

    // 2) zero p0pad (halo)
    fill0_k<<<24768, 256, 0, stream>>>((uint4*)p0pad, 6340608);

    // 3) conv3d#1 via im2col + MFMA GEMM, two od-halves
    im2col3d_k<<<15360, 256, 0, stream>>>(x3d, A3, 0);
    conv1_gemm<<<1536, 256, 0, stream>>>(A3, w13d, pb0, p0pad, 196608, 160, 0);
    im2col3d_k<<<15360, 256, 0, stream>>>(x3d, A3, 6);
    conv1_gemm<<<1536, 256, 0, stream>>>(A3, w13d, pb0, p0pad, 196608, 160, 768);

    // 4) zero p1pad+s0pad+s1pad (halos); then conv2d#1
    fill0_k<<<9344, 256, 0, stream>>>((uint4*)p1pad, 2392064);
    im2col2d_k<<<1536, 256, 0, stream>>>(x2d, A2);
    conv1_gemm<<<256, 256, 0, stream>>>(A2, w12d, sb0, s0pad, 32768, 96, 0);

    // 5) conv chains (#2/#3)
    conv_mfma2<128, 1><<<dim3(2, 64), 256, 0, stream>>>(s0pad, wr2d2, sb1, s1pad, 1, 128, 258, 128, 64, 256, 130, 1);
    conv_mfma2<64, 1><<<dim3(4, 32), 256, 0, stream>>>(s1pad, wr2d3, sb2, featsT + (size_t)6144 * 512, 1, 64, 130, 256, 32, 512, 64, 0);
    conv_mfma2<128, 3><<<dim3(2, 384), 256, 0, stream>>>(p0pad, wr3d2, pb1, p1pad, 12, 128, 258, 128, 64, 256, 130, 1);
    conv_mfma2<64, 3><<<dim3(4, 96), 256, 0, stream>>>(p1pad, wr3d3, pb2, featsT, 6, 64, 130, 256, 32, 512, 64, 0);

    // 6) lateral 1x1 conv
    gemm_bt<float, 0, 0><<<dim3(4, 64), 256, 0, stream>>>(featsT, latbf, latb, lat, nullptr, nullptr, 8192, 512, 512);

    // 7) 3 attention rounds
    for (int r = 0; r < 3; r++) {
        ln_k<<<2048, 256, 0, stream>>>(lat, lng + r * 512, lnb + r * 512, ybf);
        gemm_bt<bf16, 0, 1><<<dim3(12, 64), 256, 0, stream>>>(ybf, qkvt + (size_t)r * 786432, qkvb + r * 1536,
                                                              qkvbuf, nullptr, vT, 8192, 1536, 512);
        natt_mfma<<<dim3(128, 8), 256, 0, stream>>>(qkvbuf, vT, attno);
        gemm_bt<float, 1, 0><<<dim3(4, 64), 256, 0, stream>>>(attno, projt + (size_t)r * 262144, projb + r * 512,
                                                              lat, lat, nullptr, 8192, 512, 512);
    }

    // 8) transpose to planar output [512][4][32][64]
    tout_k<<<dim3(128, 8), 256, 0, stream>>>(lat, outp);
}